// Round 15
// baseline (1551.653 us; speedup 1.0000x reference)
//
#include <hip/hip_runtime.h>

// ---------- types / helpers ----------
typedef __bf16 bx8 __attribute__((ext_vector_type(8)));
typedef float fx4 __attribute__((ext_vector_type(4)));

#define GAS(p) ((const __attribute__((address_space(1))) void*)(const void*)(p))
#define LAS(p) ((__attribute__((address_space(3))) void*)(void*)(p))
#define WAITVM(n) do { asm volatile("s_waitcnt vmcnt(" #n ")" ::: "memory"); \
                       __builtin_amdgcn_sched_barrier(0); } while (0)
#define WAITLG0() do { asm volatile("s_waitcnt lgkmcnt(0)" ::: "memory"); \
                       __builtin_amdgcn_sched_barrier(0); } while (0)

__device__ __forceinline__ unsigned short f2bf(float f) {
  return __builtin_bit_cast(unsigned short, (__bf16)f);  // native RTNE
}

// ---------- tiled weight transpose + bf16 cast: dst[l][n][k] = (bf16)src[l][k][n] ----------
__global__ __launch_bounds__(256) void wtrans_kernel(const float* __restrict__ src,
                                                     unsigned short* __restrict__ dst,
                                                     int K, int N) {
  __shared__ unsigned short t[64][68];
  const int l = blockIdx.z;
  const float* s = src + (size_t)l * K * N;
  unsigned short* d = dst + (size_t)l * N * K;
  const int n0 = blockIdx.x * 64, k0 = blockIdx.y * 64;
  const int tx = threadIdx.x & 63, ty = threadIdx.x >> 6;
#pragma unroll
  for (int r = 0; r < 64; r += 4)
    t[tx][ty + r] = f2bf(s[(size_t)(k0 + ty + r) * N + n0 + tx]);
  __syncthreads();
#pragma unroll
  for (int r = 0; r < 64; r += 4)
    d[(size_t)(n0 + ty + r) * K + k0 + tx] = t[ty + r][tx];
}

// ---------- fused embed + ln1(layer0): one wave per row ----------
__global__ __launch_bounds__(256) void embed_ln_kernel(const float4* __restrict__ x,
                                                       const float4* __restrict__ ce,
                                                       const float4* __restrict__ pe,
                                                       const float* __restrict__ gw,
                                                       const float* __restrict__ bw,
                                                       float4* __restrict__ xres,
                                                       unsigned short* __restrict__ hn) {
  const int row = blockIdx.x * 4 + (threadIdx.x >> 6);
  const int lane = threadIdx.x & 63;
  const int t = row & 255;
  const size_t idx = (size_t)row * 64 + lane;
  float4 a = x[idx], b = ce[t * 64 + lane], p = pe[(t + 1) * 64 + lane];
  float4 v = make_float4(a.x + b.x + p.x, a.y + b.y + p.y, a.z + b.z + p.z, a.w + b.w + p.w);
  xres[idx] = v;
  float s = v.x + v.y + v.z + v.w;
  float q = v.x * v.x + v.y * v.y + v.z * v.z + v.w * v.w;
#pragma unroll
  for (int off = 1; off < 64; off <<= 1) {
    s += __shfl_xor(s, off);
    q += __shfl_xor(q, off);
  }
  float mean = s * (1.0f / 256.0f);
  float rs = rsqrtf(q * (1.0f / 256.0f) - mean * mean + 1e-5f);
  float4 gv = *(const float4*)(gw + lane * 4);
  float4 bv = *(const float4*)(bw + lane * 4);
  ushort4 o;
  o.x = f2bf((v.x - mean) * rs * gv.x + bv.x);
  o.y = f2bf((v.y - mean) * rs * gv.y + bv.y);
  o.z = f2bf((v.z - mean) * rs * gv.z + bv.z);
  o.w = f2bf((v.w - mean) * rs * gv.w + bv.w);
  *(ushort4*)(hn + (size_t)row * 256 + lane * 4) = o;
}

// ---------- final mean, two-stage ----------
__global__ __launch_bounds__(256) void mean_part_kernel(const float* __restrict__ x,
                                                        const float2* __restrict__ stats,
                                                        float* __restrict__ part) {
  int b = blockIdx.x, half = blockIdx.y, c = threadIdx.x;
  const float* xb = x + (size_t)b * 65536 + half * 32768;
  const float2* st = stats + b * 256 + half * 128;
  float acc = 0.f;
#pragma unroll 4
  for (int t = 0; t < 128; ++t) {
    float2 s = st[t];
    acc += (xb[t * 256 + c] - s.x) * s.y;
  }
  part[(size_t)(b * 2 + half) * 256 + c] = acc;
}
__global__ __launch_bounds__(256) void mean_fin_kernel(const float* __restrict__ part,
                                                       const float* __restrict__ fg,
                                                       const float* __restrict__ fb,
                                                       float* __restrict__ out) {
  int b = blockIdx.x, c = threadIdx.x;
  out[b * 256 + c] =
      (part[(size_t)(2 * b) * 256 + c] + part[(size_t)(2 * b + 1) * 256 + c]) *
          (1.0f / 256.0f) * fg[c] + fb[c];
}

// ---------- GEMM 128x128: 3-BUFFER ring, DEPTH-2 prefetch (4 loads/stage) ----------
// EP 1: out_bf16 = gelu_exact(acc + bvec)
// EP 4: qkv: cols<512 -> outb; cols>=512 (V) -> vT in attn-Vl swizzled image
template <int EP>
__global__ __launch_bounds__(256) void gemm_kernel(const unsigned short* __restrict__ A,
                                                   const unsigned short* __restrict__ BT,
                                                   const float* __restrict__ bvec,
                                                   float* __restrict__ resid,
                                                   unsigned short* __restrict__ outb,
                                                   int N, int K) {
  __shared__ unsigned short lA[3][128 * 32];
  __shared__ unsigned short lB[3][128 * 32];
  const int tid = threadIdx.x;
  const int lane = tid & 63, w = tid >> 6;
  const int wr = w >> 1, wc = w & 1;
  const int g = lane >> 4, lr = lane & 15;
  const int m0 = blockIdx.y * 128, n0 = blockIdx.x * 128;
  fx4 acc[4][4] = {};

  auto STAGE = [&](int buf, int kk) {
#pragma unroll
    for (int r = 0; r < 2; ++r) {
      int u = r * 256 + tid;
      int row = u >> 2, sl = u & 3;
      int c = sl ^ ((row >> 1) & 3);
      __builtin_amdgcn_global_load_lds(GAS(A + (size_t)(m0 + row) * K + kk + c * 8),
                                       LAS(&lA[buf][u * 8]), 16, 0, 0);
      __builtin_amdgcn_global_load_lds(GAS(BT + (size_t)(n0 + row) * K + kk + c * 8),
                                       LAS(&lB[buf][u * 8]), 16, 0, 0);
    }
  };

  const int nt = K >> 5;
  STAGE(0, 0);
  STAGE(1, 32);
  STAGE(2, 64);
  int buf = 0;
  for (int t = 0; t < nt; ++t) {
    if (t < nt - 2) WAITVM(8); else if (t == nt - 2) WAITVM(4); else WAITVM(0);
    __builtin_amdgcn_s_barrier();
    bx8 af[4], bq[4];
#pragma unroll
    for (int i = 0; i < 4; ++i) {
      int row = wr * 64 + i * 16 + lr;
      af[i] = *(const bx8*)&lA[buf][row * 32 + (g ^ ((row >> 1) & 3)) * 8];
      int col = wc * 64 + i * 16 + lr;
      bq[i] = *(const bx8*)&lB[buf][col * 32 + (g ^ ((col >> 1) & 3)) * 8];
    }
    WAITLG0();
    __builtin_amdgcn_s_barrier();
    if (t + 3 < nt) STAGE(buf, (t + 3) * 32);
#pragma unroll
    for (int i = 0; i < 4; ++i)
#pragma unroll
      for (int j = 0; j < 4; ++j)
        acc[i][j] = __builtin_amdgcn_mfma_f32_16x16x32_bf16(bq[j], af[i], acc[i][j], 0, 0, 0);
    buf = (buf == 2) ? 0 : buf + 1;
  }

#pragma unroll
  for (int i = 0; i < 4; ++i) {
    const int m = m0 + wr * 64 + i * 16 + lr;
#pragma unroll
    for (int j = 0; j < 4; ++j) {
      const int nc = n0 + wc * 64 + j * 16 + g * 4;
      const float4 bv = *(const float4*)(bvec + nc);
      float v0 = acc[i][j][0] + bv.x, v1 = acc[i][j][1] + bv.y;
      float v2 = acc[i][j][2] + bv.z, v3 = acc[i][j][3] + bv.w;
      if constexpr (EP == 1) {
        v0 = 0.5f * v0 * (1.0f + erff(v0 * 0.70710678118654752f));
        v1 = 0.5f * v1 * (1.0f + erff(v1 * 0.70710678118654752f));
        v2 = 0.5f * v2 * (1.0f + erff(v2 * 0.70710678118654752f));
        v3 = 0.5f * v3 * (1.0f + erff(v3 * 0.70710678118654752f));
      }
      if constexpr (EP == 1) {
        ushort4 st;
        st.x = f2bf(v0); st.y = f2bf(v1); st.z = f2bf(v2); st.w = f2bf(v3);
        *(ushort4*)(outb + (size_t)m * N + nc) = st;
      } else {  // EP 4
        if (nc < 512) {
          ushort4 st;
          st.x = f2bf(v0); st.y = f2bf(v1); st.z = f2bf(v2); st.w = f2bf(v3);
          *(ushort4*)(outb + (size_t)m * N + nc) = st;
        } else {
          unsigned short* vTp = (unsigned short*)resid;
          const int s = m & 255, b = m >> 8;
          const int hv = nc - 512;
          const int h = hv >> 5, d0 = hv & 31;
          const int jj = (s & 3) + 4 * ((s >> 4) & 1);
          const int ub = (s >> 5) * 128 + ((s >> 2) & 3) * 32 + d0;
          unsigned short* base = vTp + (size_t)(b * 8 + h) * 8192;
          const float vv[4] = {v0, v1, v2, v3};
#pragma unroll
          for (int r = 0; r < 4; ++r) {
            int u = ub + r;
            int up = (u & ~7) | ((u & 7) ^ ((u >> 3) & 7));
            base[up * 8 + jj] = f2bf(vv[r]);
          }
        }
      }
    }
  }
}

// ---------- GEMM 32x256 + residual + FUSED LN (2-buffer, 4 blocks/CU) ----------
// EP 2: v = acc + bvec + col_bias[m&255][nc] + x_res   (proj path)
// EP 3: v = acc + bvec + x_res                          (W3 path)
// LNM 0: hn = (v-mean)*rs*lnw+lnb; LNM 1: stats[m]=(mean,rs).
template <int EP, int LNM>
__global__ __launch_bounds__(256) void gemm_ln_kernel(const unsigned short* __restrict__ A,
                                                      const unsigned short* __restrict__ BT,
                                                      const float* __restrict__ bvec,
                                                      const float* __restrict__ cbias,
                                                      float* __restrict__ resid,
                                                      const float* __restrict__ lnw,
                                                      const float* __restrict__ lnb,
                                                      unsigned short* __restrict__ hn,
                                                      float2* __restrict__ stats,
                                                      int K) {
  __shared__ unsigned short lA[2][32 * 32];
  __shared__ unsigned short lB[2][256 * 32];
  __shared__ float2 red[4][32];
  const int tid = threadIdx.x;
  const int lane = tid & 63, w = tid >> 6;
  const int g = lane >> 4, lr = lane & 15;
  const int m0 = blockIdx.x * 32;
  fx4 acc[2][4] = {};

  auto STAGE = [&](int buf, int kk) {
    {
      int u = tid & 127;  // duplicated across thread halves (identical data)
      int row = u >> 2, sl = u & 3;
      int c = sl ^ ((row >> 1) & 3);
      __builtin_amdgcn_global_load_lds(GAS(A + (size_t)(m0 + row) * K + kk + c * 8),
                                       LAS(&lA[buf][u * 8]), 16, 0, 0);
    }
#pragma unroll
    for (int r = 0; r < 4; ++r) {
      int u = r * 256 + tid;
      int row = u >> 2, sl = u & 3;
      int c = sl ^ ((row >> 1) & 3);
      __builtin_amdgcn_global_load_lds(GAS(BT + (size_t)row * K + kk + c * 8),
                                       LAS(&lB[buf][u * 8]), 16, 0, 0);
    }
  };

  const int nt = K >> 5;
  STAGE(0, 0);
  STAGE(1, 32);
  for (int t = 0; t < nt; ++t) {
    if (t == nt - 1) WAITVM(0); else WAITVM(5);
    __builtin_amdgcn_s_barrier();
    const int buf = t & 1;
    bx8 af[2], bq[4];
#pragma unroll
    for (int i = 0; i < 2; ++i) {
      int row = i * 16 + lr;
      af[i] = *(const bx8*)&lA[buf][row * 32 + (g ^ ((row >> 1) & 3)) * 8];
    }
#pragma unroll
    for (int j = 0; j < 4; ++j) {
      int col = w * 64 + j * 16 + lr;
      bq[j] = *(const bx8*)&lB[buf][col * 32 + (g ^ ((col >> 1) & 3)) * 8];
    }
    WAITLG0();
    __builtin_amdgcn_s_barrier();
    if (t + 2 < nt) STAGE(buf, (t + 2) * 32);
#pragma unroll
    for (int i = 0; i < 2; ++i)
#pragma unroll
      for (int j = 0; j < 4; ++j)
        acc[i][j] = __builtin_amdgcn_mfma_f32_16x16x32_bf16(bq[j], af[i], acc[i][j], 0, 0, 0);
  }

  // epilogue: v in acc, RMW x_res, per-row LN reduce
  float s[2] = {0.f, 0.f}, q[2] = {0.f, 0.f};
#pragma unroll
  for (int i = 0; i < 2; ++i) {
    const int m = m0 + i * 16 + lr;
#pragma unroll
    for (int j = 0; j < 4; ++j) {
      const int nc = w * 64 + j * 16 + g * 4;
      const float4 bv = *(const float4*)(bvec + nc);
      float v0 = acc[i][j][0] + bv.x, v1 = acc[i][j][1] + bv.y;
      float v2 = acc[i][j][2] + bv.z, v3 = acc[i][j][3] + bv.w;
      if constexpr (EP == 2) {
        const float4 cb = *(const float4*)(cbias + (size_t)(m & 255) * 256 + nc);
        v0 += cb.x; v1 += cb.y; v2 += cb.z; v3 += cb.w;
      }
      float4* rp = (float4*)(resid + (size_t)m * 256 + nc);
      float4 old = *rp;
      v0 += old.x; v1 += old.y; v2 += old.z; v3 += old.w;
      *rp = make_float4(v0, v1, v2, v3);
      acc[i][j][0] = v0; acc[i][j][1] = v1; acc[i][j][2] = v2; acc[i][j][3] = v3;
      s[i] += v0 + v1 + v2 + v3;
      q[i] += v0 * v0 + v1 * v1 + v2 * v2 + v3 * v3;
    }
  }
#pragma unroll
  for (int i = 0; i < 2; ++i) {
    s[i] += __shfl_xor(s[i], 16); s[i] += __shfl_xor(s[i], 32);
    q[i] += __shfl_xor(q[i], 16); q[i] += __shfl_xor(q[i], 32);
  }
  if (lane < 16) {
#pragma unroll
    for (int i = 0; i < 2; ++i) red[w][i * 16 + lr] = make_float2(s[i], q[i]);
  }
  __syncthreads();
  float mean[2], rs[2];
#pragma unroll
  for (int i = 0; i < 2; ++i) {
    float2 r0 = red[0][i * 16 + lr], r1 = red[1][i * 16 + lr];
    float2 r2 = red[2][i * 16 + lr], r3 = red[3][i * 16 + lr];
    float S = r0.x + r1.x + r2.x + r3.x;
    float Q = r0.y + r1.y + r2.y + r3.y;
    mean[i] = S * (1.0f / 256.0f);
    rs[i] = rsqrtf(Q * (1.0f / 256.0f) - mean[i] * mean[i] + 1e-5f);
  }
  if constexpr (LNM == 1) {
    if (w == 0 && g == 0) {
#pragma unroll
      for (int i = 0; i < 2; ++i) stats[m0 + i * 16 + lr] = make_float2(mean[i], rs[i]);
    }
  } else {
#pragma unroll
    for (int i = 0; i < 2; ++i) {
      const int m = m0 + i * 16 + lr;
#pragma unroll
      for (int j = 0; j < 4; ++j) {
        const int nc = w * 64 + j * 16 + g * 4;
        const float4 gv = *(const float4*)(lnw + nc);
        const float4 bv2 = *(const float4*)(lnb + nc);
        ushort4 st;
        st.x = f2bf((acc[i][j][0] - mean[i]) * rs[i] * gv.x + bv2.x);
        st.y = f2bf((acc[i][j][1] - mean[i]) * rs[i] * gv.y + bv2.y);
        st.z = f2bf((acc[i][j][2] - mean[i]) * rs[i] * gv.z + bv2.z);
        st.w = f2bf((acc[i][j][3] - mean[i]) * rs[i] * gv.w + bv2.w);
        *(ushort4*)(hn + (size_t)m * 256 + nc) = st;
      }
    }
  }
}

// ---------- fused W2+swiglu BM=64: 3-buffer ring, DEPTH-2 prefetch (proven 58.9us) ----------
__global__ __launch_bounds__(256) void gemm_w2f64_kernel(const unsigned short* __restrict__ A,
                                                         const unsigned short* __restrict__ BT,
                                                         const float* __restrict__ b2,
                                                         unsigned short* __restrict__ gout) {
  __shared__ unsigned short lA[3][64 * 32];
  __shared__ unsigned short lBa[3][128 * 32];
  __shared__ unsigned short lBg[3][128 * 32];
  const int tid = threadIdx.x;
  const int lane = tid & 63, w = tid >> 6;
  const int g = lane >> 4, lr = lane & 15;
  const int m0 = blockIdx.y * 64, n0 = blockIdx.x * 128;
  fx4 aA[4][2] = {}, aG[4][2] = {};

  auto STAGE = [&](int buf, int kk) {
    {
      int u = tid;
      int row = u >> 2, sl = u & 3;
      int c = sl ^ ((row >> 1) & 3);
      __builtin_amdgcn_global_load_lds(GAS(A + (size_t)(m0 + row) * 1024 + kk + c * 8),
                                       LAS(&lA[buf][u * 8]), 16, 0, 0);
    }
#pragma unroll
    for (int r = 0; r < 2; ++r) {
      int u = r * 256 + tid;
      int row = u >> 2, sl = u & 3;
      int c = sl ^ ((row >> 1) & 3);
      __builtin_amdgcn_global_load_lds(GAS(BT + (size_t)(n0 + row) * 1024 + kk + c * 8),
                                       LAS(&lBa[buf][u * 8]), 16, 0, 0);
      __builtin_amdgcn_global_load_lds(GAS(BT + (size_t)(256 + n0 + row) * 1024 + kk + c * 8),
                                       LAS(&lBg[buf][u * 8]), 16, 0, 0);
    }
  };

  STAGE(0, 0);
  STAGE(1, 32);
  STAGE(2, 64);
  int buf = 0;
  for (int t = 0; t < 32; ++t) {
    if (t < 30) WAITVM(10); else if (t == 30) WAITVM(5); else WAITVM(0);
    __builtin_amdgcn_s_barrier();
    bx8 af[4], ba[2], bg[2];
#pragma unroll
    for (int i = 0; i < 4; ++i) {
      int row = i * 16 + lr;
      af[i] = *(const bx8*)&lA[buf][row * 32 + (g ^ ((row >> 1) & 3)) * 8];
    }
#pragma unroll
    for (int j = 0; j < 2; ++j) {
      int col = w * 32 + j * 16 + lr;
      int sw = (g ^ ((col >> 1) & 3)) * 8;
      ba[j] = *(const bx8*)&lBa[buf][col * 32 + sw];
      bg[j] = *(const bx8*)&lBg[buf][col * 32 + sw];
    }
    WAITLG0();
    __builtin_amdgcn_s_barrier();
    if (t + 3 < 32) STAGE(buf, (t + 3) * 32);  // reuse just-consumed buffer
#pragma unroll
    for (int i = 0; i < 4; ++i)
#pragma unroll
      for (int j = 0; j < 2; ++j) {
        aA[i][j] = __builtin_amdgcn_mfma_f32_16x16x32_bf16(ba[j], af[i], aA[i][j], 0, 0, 0);
        aG[i][j] = __builtin_amdgcn_mfma_f32_16x16x32_bf16(bg[j], af[i], aG[i][j], 0, 0, 0);
      }
    buf = (buf == 2) ? 0 : buf + 1;
  }

#pragma unroll
  for (int i = 0; i < 4; ++i) {
    const int m = m0 + i * 16 + lr;
#pragma unroll
    for (int j = 0; j < 2; ++j) {
      const int nc = n0 + w * 32 + j * 16 + g * 4;
      const float4 bva = *(const float4*)(b2 + nc);
      const float4 bvg = *(const float4*)(b2 + 256 + nc);
      float a0 = aA[i][j][0] + bva.x, a1 = aA[i][j][1] + bva.y;
      float a2 = aA[i][j][2] + bva.z, a3 = aA[i][j][3] + bva.w;
      float g0 = aG[i][j][0] + bvg.x, g1 = aG[i][j][1] + bvg.y;
      float g2 = aG[i][j][2] + bvg.z, g3 = aG[i][j][3] + bvg.w;
      ushort4 st;
      st.x = f2bf(a0 / (1.0f + __expf(-g0)));
      st.y = f2bf(a1 / (1.0f + __expf(-g1)));
      st.z = f2bf(a2 / (1.0f + __expf(-g2)));
      st.w = f2bf(a3 / (1.0f + __expf(-g3)));
      *(ushort4*)(gout + (size_t)m * 256 + nc) = st;
    }
  }
}

// ---------- fused attention v4: ONE q-tile per block (grid 1024 x 4) ----------
// Round-14 attn was latency-bound (Occ ~20%, nothing busy): 1024 blocks, each
// serializing 4 q-tile iterations. Split iterations across blockIdx.y -> 4096
// blocks; K/V staging repeated (L2-hot, cheap) but softmax dependency chains of
// different q-tiles now interleave across waves. Single Q frag loaded during
// staging (no round-11 4-frag pressure).
__global__ __launch_bounds__(256) void attn_kernel(const unsigned short* __restrict__ qkv,
                                                   const unsigned short* __restrict__ vT,
                                                   const float* __restrict__ cbias,
                                                   unsigned short* __restrict__ attnb) {
  __shared__ unsigned short Kl[256 * 32];
  __shared__ unsigned short Vl[1024 * 8];
  const int bh = blockIdx.x, b = bh >> 3, h = bh & 7;
  const int it = blockIdx.y;
  const int tid = threadIdx.x, lane = tid & 63, w = tid >> 6;
  const int g = lane >> 4, lr = lane & 15;
  const unsigned short* qb_ = qkv + (size_t)b * 196608;
  const unsigned short* vTb = vT + (size_t)bh * 8192;
#pragma unroll
  for (int r = 0; r < 4; ++r) {
    int u = r * 256 + tid;
    int s = u >> 2, sl = u & 3;
    int c = sl ^ ((s >> 1) & 3);
    __builtin_amdgcn_global_load_lds(GAS(qb_ + (size_t)s * 768 + 256 + h * 32 + c * 8),
                                     LAS(&Kl[u * 8]), 16, 0, 0);
    __builtin_amdgcn_global_load_lds(GAS(vTb + u * 8), LAS(&Vl[u * 8]), 16, 0, 0);
  }
  const int t = it * 64 + w * 16 + lr;
  bx8 qf = *(const bx8*)(qb_ + (size_t)t * 768 + h * 32 + g * 8);  // overlaps staging
  asm volatile("s_waitcnt vmcnt(0)" ::: "memory");
  __syncthreads();
  const float scale = 0.17677669529663689f;
  const fx4 zero = {0.f, 0.f, 0.f, 0.f};
  float p[16][4];
  float mx = -1e30f;
#pragma unroll
  for (int n = 0; n < 16; ++n) {
    int sr = n * 16 + lr;
    bx8 kf = *(const bx8*)&Kl[sr * 32 + (g ^ ((sr >> 1) & 3)) * 8];
    fx4 sc = __builtin_amdgcn_mfma_f32_16x16x32_bf16(kf, qf, zero, 0, 0, 0);
    const float4 cb = *(const float4*)(cbias + (size_t)t * 256 + n * 16 + g * 4);
    p[n][0] = sc[0] * scale + cb.x;
    p[n][1] = sc[1] * scale + cb.y;
    p[n][2] = sc[2] * scale + cb.z;
    p[n][3] = sc[3] * scale + cb.w;
    mx = fmaxf(mx, fmaxf(fmaxf(p[n][0], p[n][1]), fmaxf(p[n][2], p[n][3])));
  }
  mx = fmaxf(mx, __shfl_xor(mx, 16));
  mx = fmaxf(mx, __shfl_xor(mx, 32));
  float sum = 0.f;
  bx8 bq[8];
#pragma unroll
  for (int c = 0; c < 8; ++c) {
    union { bx8 v; unsigned short u[8]; } pk;
#pragma unroll
    for (int jj = 0; jj < 8; ++jj) {
      float e = __expf(p[2 * c + (jj >> 2)][jj & 3] - mx);
      sum += e;
      pk.u[jj] = f2bf(e);
    }
    bq[c] = pk.v;
  }
  sum += __shfl_xor(sum, 16);
  sum += __shfl_xor(sum, 32);
  const float inv = 1.0f / sum;
  fx4 oa0 = zero, oa1 = zero;
#pragma unroll
  for (int c = 0; c < 8; ++c) {
    int u0 = c * 128 + g * 32 + lr;
    int u0p = (u0 & ~7) | ((u0 & 7) ^ ((u0 >> 3) & 7));
    bx8 vf0 = *(const bx8*)&Vl[u0p * 8];
    oa0 = __builtin_amdgcn_mfma_f32_16x16x32_bf16(vf0, bq[c], oa0, 0, 0, 0);
    int u1 = u0 + 16;
    int u1p = (u1 & ~7) | ((u1 & 7) ^ ((u1 >> 3) & 7));
    bx8 vf1 = *(const bx8*)&Vl[u1p * 8];
    oa1 = __builtin_amdgcn_mfma_f32_16x16x32_bf16(vf1, bq[c], oa1, 0, 0, 0);
  }
  ushort4 o0, o1;
  o0.x = f2bf(oa0[0] * inv); o0.y = f2bf(oa0[1] * inv);
  o0.z = f2bf(oa0[2] * inv); o0.w = f2bf(oa0[3] * inv);
  o1.x = f2bf(oa1[0] * inv); o1.y = f2bf(oa1[1] * inv);
  o1.z = f2bf(oa1[2] * inv); o1.w = f2bf(oa1[3] * inv);
  unsigned short* orow = attnb + (size_t)(b * 256 + t) * 256 + h * 32;
  *(ushort4*)(orow + 4 * g) = o0;
  *(ushort4*)(orow + 16 + 4 * g) = o1;
}

// ---------- orchestration ----------
extern "C" void kernel_launch(void* const* d_in, const int* in_sizes, int n_in,
                              void* d_out, int out_size, void* d_ws, size_t ws_size,
                              hipStream_t stream) {
  (void)in_sizes; (void)n_in; (void)out_size; (void)ws_size;
  const float* x     = (const float*)d_in[0];
  const float* cemb  = (const float*)d_in[1];
  const float* pemb  = (const float*)d_in[2];
  const float* cbias = (const float*)d_in[3];
  const float* ln1g  = (const float*)d_in[4];
  const float* ln1b  = (const float*)d_in[5];
  const float* qkvw  = (const float*)d_in[6];
  const float* qkvb  = (const float*)d_in[7];
  const float* outw  = (const float*)d_in[8];
  const float* outbv = (const float*)d_in[9];
  const float* ln2g  = (const float*)d_in[10];
  const float* ln2b  = (const float*)d_in[11];
  const float* w1    = (const float*)d_in[12];
  const float* b1    = (const float*)d_in[13];
  const float* w2    = (const float*)d_in[14];
  const float* b2    = (const float*)d_in[15];
  const float* w3    = (const float*)d_in[16];
  const float* b3    = (const float*)d_in[17];
  const float* fing  = (const float*)d_in[18];
  const float* finb  = (const float*)d_in[19];

  char* ws = (char*)d_ws;
  float* x_res = (float*)(ws);
  unsigned short* hn   = (unsigned short*)(ws + 33554432);
  unsigned short* big  = (unsigned short*)(ws + 50331648);
  unsigned short* vT   = (unsigned short*)(ws + 100663296);
  unsigned short* wT   = (unsigned short*)(ws + 117440512);
  float2* stats = (float2*)(ws + 130809856);
  float* part  = (float*)big;  // mean partials: big dead by then

  unsigned short* qkvwT = wT;                 // 6*768*256
  unsigned short* outwT = wT + 1179648;       // 6*256*256
  unsigned short* w1T   = wT + 1572864;       // 6*1024*256
  unsigned short* w2T   = wT + 3145728;       // 6*512*1024
  unsigned short* w3T   = wT + 6291456;       // 6*256*256

  wtrans_kernel<<<dim3(12, 4, 6), 256, 0, stream>>>(qkvw, qkvwT, 256, 768);
  wtrans_kernel<<<dim3(4, 4, 6), 256, 0, stream>>>(outw, outwT, 256, 256);
  wtrans_kernel<<<dim3(16, 4, 6), 256, 0, stream>>>(w1, w1T, 256, 1024);
  wtrans_kernel<<<dim3(8, 16, 6), 256, 0, stream>>>(w2, w2T, 1024, 512);
  wtrans_kernel<<<dim3(4, 4, 6), 256, 0, stream>>>(w3, w3T, 256, 256);
  embed_ln_kernel<<<8192, 256, 0, stream>>>((const float4*)x, (const float4*)cemb,
                                            (const float4*)pemb, ln1g, ln1b,
                                            (float4*)x_res, hn);
  for (int l = 0; l < 6; ++l) {
    gemm_kernel<4><<<dim3(6, 256), 256, 0, stream>>>(hn, qkvwT + (size_t)l * 196608,
                                                     qkvb + l * 768, (float*)vT, big,
                                                     768, 256);
    attn_kernel<<<dim3(1024, 4), 256, 0, stream>>>(big, vT, cbias, hn);
    gemm_ln_kernel<2, 0><<<1024, 256, 0, stream>>>(hn, outwT + (size_t)l * 65536,
                                                   outbv + l * 256, cbias, x_res,
                                                   ln2g + l * 256, ln2b + l * 256, hn,
                                                   nullptr, 256);
    gemm_kernel<1><<<dim3(8, 256), 256, 0, stream>>>(hn, w1T + (size_t)l * 262144,
                                                     b1 + l * 1024, nullptr, big,
                                                     1024, 256);
    gemm_w2f64_kernel<<<dim3(2, 512), 256, 0, stream>>>(big, w2T + (size_t)l * 524288,
                                                        b2 + l * 512, hn);
    if (l < 5) {
      gemm_ln_kernel<3, 0><<<1024, 256, 0, stream>>>(hn, w3T + (size_t)l * 65536,
                                                     b3 + l * 256, nullptr, x_res,
                                                     ln1g + (l + 1) * 256,
                                                     ln1b + (l + 1) * 256, hn,
                                                     nullptr, 256);
    } else {
      gemm_ln_kernel<3, 1><<<1024, 256, 0, stream>>>(hn, w3T + (size_t)l * 65536,
                                                     b3 + l * 256, nullptr, x_res,
                                                     nullptr, nullptr, nullptr,
                                                     stats, 256);
    }
  }
  mean_part_kernel<<<dim3(128, 2), 256, 0, stream>>>(x_res, stats, part);
  mean_fin_kernel<<<128, 256, 0, stream>>>(part, fing, finb, (float*)d_out);
}

// Round 16
// 1489.683 us; speedup vs baseline: 1.0416x; 1.0416x over previous
//
#include <hip/hip_runtime.h>

// ---------- types / helpers ----------
typedef __bf16 bx8 __attribute__((ext_vector_type(8)));
typedef float fx4 __attribute__((ext_vector_type(4)));

#define GAS(p) ((const __attribute__((address_space(1))) void*)(const void*)(p))
#define LAS(p) ((__attribute__((address_space(3))) void*)(void*)(p))
#define WAITVM(n) do { asm volatile("s_waitcnt vmcnt(" #n ")" ::: "memory"); \
                       __builtin_amdgcn_sched_barrier(0); } while (0)
#define WAITLG0() do { asm volatile("s_waitcnt lgkmcnt(0)" ::: "memory"); \
                       __builtin_amdgcn_sched_barrier(0); } while (0)

__device__ __forceinline__ unsigned short f2bf(float f) {
  return __builtin_bit_cast(unsigned short, (__bf16)f);  // native RTNE
}

// ---------- tiled weight transpose + bf16 cast: dst[l][n][k] = (bf16)src[l][k][n] ----------
__global__ __launch_bounds__(256) void wtrans_kernel(const float* __restrict__ src,
                                                     unsigned short* __restrict__ dst,
                                                     int K, int N) {
  __shared__ unsigned short t[64][68];
  const int l = blockIdx.z;
  const float* s = src + (size_t)l * K * N;
  unsigned short* d = dst + (size_t)l * N * K;
  const int n0 = blockIdx.x * 64, k0 = blockIdx.y * 64;
  const int tx = threadIdx.x & 63, ty = threadIdx.x >> 6;
#pragma unroll
  for (int r = 0; r < 64; r += 4)
    t[tx][ty + r] = f2bf(s[(size_t)(k0 + ty + r) * N + n0 + tx]);
  __syncthreads();
#pragma unroll
  for (int r = 0; r < 64; r += 4)
    d[(size_t)(n0 + ty + r) * K + k0 + tx] = t[ty + r][tx];
}

// ---------- fused embed + ln1(layer0): one wave per row ----------
__global__ __launch_bounds__(256) void embed_ln_kernel(const float4* __restrict__ x,
                                                       const float4* __restrict__ ce,
                                                       const float4* __restrict__ pe,
                                                       const float* __restrict__ gw,
                                                       const float* __restrict__ bw,
                                                       float4* __restrict__ xres,
                                                       unsigned short* __restrict__ hn) {
  const int row = blockIdx.x * 4 + (threadIdx.x >> 6);
  const int lane = threadIdx.x & 63;
  const int t = row & 255;
  const size_t idx = (size_t)row * 64 + lane;
  float4 a = x[idx], b = ce[t * 64 + lane], p = pe[(t + 1) * 64 + lane];
  float4 v = make_float4(a.x + b.x + p.x, a.y + b.y + p.y, a.z + b.z + p.z, a.w + b.w + p.w);
  xres[idx] = v;
  float s = v.x + v.y + v.z + v.w;
  float q = v.x * v.x + v.y * v.y + v.z * v.z + v.w * v.w;
#pragma unroll
  for (int off = 1; off < 64; off <<= 1) {
    s += __shfl_xor(s, off);
    q += __shfl_xor(q, off);
  }
  float mean = s * (1.0f / 256.0f);
  float rs = rsqrtf(q * (1.0f / 256.0f) - mean * mean + 1e-5f);
  float4 gv = *(const float4*)(gw + lane * 4);
  float4 bv = *(const float4*)(bw + lane * 4);
  ushort4 o;
  o.x = f2bf((v.x - mean) * rs * gv.x + bv.x);
  o.y = f2bf((v.y - mean) * rs * gv.y + bv.y);
  o.z = f2bf((v.z - mean) * rs * gv.z + bv.z);
  o.w = f2bf((v.w - mean) * rs * gv.w + bv.w);
  *(ushort4*)(hn + (size_t)row * 256 + lane * 4) = o;
}

// ---------- final mean, two-stage ----------
__global__ __launch_bounds__(256) void mean_part_kernel(const float* __restrict__ x,
                                                        const float2* __restrict__ stats,
                                                        float* __restrict__ part) {
  int b = blockIdx.x, half = blockIdx.y, c = threadIdx.x;
  const float* xb = x + (size_t)b * 65536 + half * 32768;
  const float2* st = stats + b * 256 + half * 128;
  float acc = 0.f;
#pragma unroll 4
  for (int t = 0; t < 128; ++t) {
    float2 s = st[t];
    acc += (xb[t * 256 + c] - s.x) * s.y;
  }
  part[(size_t)(b * 2 + half) * 256 + c] = acc;
}
__global__ __launch_bounds__(256) void mean_fin_kernel(const float* __restrict__ part,
                                                       const float* __restrict__ fg,
                                                       const float* __restrict__ fb,
                                                       float* __restrict__ out) {
  int b = blockIdx.x, c = threadIdx.x;
  out[b * 256 + c] =
      (part[(size_t)(2 * b) * 256 + c] + part[(size_t)(2 * b + 1) * 256 + c]) *
          (1.0f / 256.0f) * fg[c] + fb[c];
}

// ---------- GEMM 128x128: 3-BUFFER ring, DEPTH-2 prefetch (4 loads/stage) ----------
// EP 1: out_bf16 = gelu_exact(acc + bvec)
// EP 4: qkv: cols<512 -> outb; cols>=512 (V) -> vT in attn-Vl swizzled image
template <int EP>
__global__ __launch_bounds__(256) void gemm_kernel(const unsigned short* __restrict__ A,
                                                   const unsigned short* __restrict__ BT,
                                                   const float* __restrict__ bvec,
                                                   float* __restrict__ resid,
                                                   unsigned short* __restrict__ outb,
                                                   int N, int K) {
  __shared__ unsigned short lA[3][128 * 32];
  __shared__ unsigned short lB[3][128 * 32];
  const int tid = threadIdx.x;
  const int lane = tid & 63, w = tid >> 6;
  const int wr = w >> 1, wc = w & 1;
  const int g = lane >> 4, lr = lane & 15;
  const int m0 = blockIdx.y * 128, n0 = blockIdx.x * 128;
  fx4 acc[4][4] = {};

  auto STAGE = [&](int buf, int kk) {
#pragma unroll
    for (int r = 0; r < 2; ++r) {
      int u = r * 256 + tid;
      int row = u >> 2, sl = u & 3;
      int c = sl ^ ((row >> 1) & 3);
      __builtin_amdgcn_global_load_lds(GAS(A + (size_t)(m0 + row) * K + kk + c * 8),
                                       LAS(&lA[buf][u * 8]), 16, 0, 0);
      __builtin_amdgcn_global_load_lds(GAS(BT + (size_t)(n0 + row) * K + kk + c * 8),
                                       LAS(&lB[buf][u * 8]), 16, 0, 0);
    }
  };

  const int nt = K >> 5;
  STAGE(0, 0);
  STAGE(1, 32);
  STAGE(2, 64);
  int buf = 0;
  for (int t = 0; t < nt; ++t) {
    if (t < nt - 2) WAITVM(8); else if (t == nt - 2) WAITVM(4); else WAITVM(0);
    __builtin_amdgcn_s_barrier();
    bx8 af[4], bq[4];
#pragma unroll
    for (int i = 0; i < 4; ++i) {
      int row = wr * 64 + i * 16 + lr;
      af[i] = *(const bx8*)&lA[buf][row * 32 + (g ^ ((row >> 1) & 3)) * 8];
      int col = wc * 64 + i * 16 + lr;
      bq[i] = *(const bx8*)&lB[buf][col * 32 + (g ^ ((col >> 1) & 3)) * 8];
    }
    WAITLG0();
    __builtin_amdgcn_s_barrier();
    if (t + 3 < nt) STAGE(buf, (t + 3) * 32);
#pragma unroll
    for (int i = 0; i < 4; ++i)
#pragma unroll
      for (int j = 0; j < 4; ++j)
        acc[i][j] = __builtin_amdgcn_mfma_f32_16x16x32_bf16(bq[j], af[i], acc[i][j], 0, 0, 0);
    buf = (buf == 2) ? 0 : buf + 1;
  }

#pragma unroll
  for (int i = 0; i < 4; ++i) {
    const int m = m0 + wr * 64 + i * 16 + lr;
#pragma unroll
    for (int j = 0; j < 4; ++j) {
      const int nc = n0 + wc * 64 + j * 16 + g * 4;
      const float4 bv = *(const float4*)(bvec + nc);
      float v0 = acc[i][j][0] + bv.x, v1 = acc[i][j][1] + bv.y;
      float v2 = acc[i][j][2] + bv.z, v3 = acc[i][j][3] + bv.w;
      if constexpr (EP == 1) {
        v0 = 0.5f * v0 * (1.0f + erff(v0 * 0.70710678118654752f));
        v1 = 0.5f * v1 * (1.0f + erff(v1 * 0.70710678118654752f));
        v2 = 0.5f * v2 * (1.0f + erff(v2 * 0.70710678118654752f));
        v3 = 0.5f * v3 * (1.0f + erff(v3 * 0.70710678118654752f));
      }
      if constexpr (EP == 1) {
        ushort4 st;
        st.x = f2bf(v0); st.y = f2bf(v1); st.z = f2bf(v2); st.w = f2bf(v3);
        *(ushort4*)(outb + (size_t)m * N + nc) = st;
      } else {  // EP 4
        if (nc < 512) {
          ushort4 st;
          st.x = f2bf(v0); st.y = f2bf(v1); st.z = f2bf(v2); st.w = f2bf(v3);
          *(ushort4*)(outb + (size_t)m * N + nc) = st;
        } else {
          unsigned short* vTp = (unsigned short*)resid;
          const int s = m & 255, b = m >> 8;
          const int hv = nc - 512;
          const int h = hv >> 5, d0 = hv & 31;
          const int jj = (s & 3) + 4 * ((s >> 4) & 1);
          const int ub = (s >> 5) * 128 + ((s >> 2) & 3) * 32 + d0;
          unsigned short* base = vTp + (size_t)(b * 8 + h) * 8192;
          const float vv[4] = {v0, v1, v2, v3};
#pragma unroll
          for (int r = 0; r < 4; ++r) {
            int u = ub + r;
            int up = (u & ~7) | ((u & 7) ^ ((u >> 3) & 7));
            base[up * 8 + jj] = f2bf(vv[r]);
          }
        }
      }
    }
  }
}

// ---------- GEMM 32x256 + residual + FUSED LN (2-buffer, 4 blocks/CU) ----------
// EP 2: v = acc + bvec + col_bias[m&255][nc] + x_res   (proj path)
// EP 3: v = acc + bvec + x_res                          (W3 path)
// LNM 0: hn = (v-mean)*rs*lnw+lnb; LNM 1: stats[m]=(mean,rs).
template <int EP, int LNM>
__global__ __launch_bounds__(256) void gemm_ln_kernel(const unsigned short* __restrict__ A,
                                                      const unsigned short* __restrict__ BT,
                                                      const float* __restrict__ bvec,
                                                      const float* __restrict__ cbias,
                                                      float* __restrict__ resid,
                                                      const float* __restrict__ lnw,
                                                      const float* __restrict__ lnb,
                                                      unsigned short* __restrict__ hn,
                                                      float2* __restrict__ stats,
                                                      int K) {
  __shared__ unsigned short lA[2][32 * 32];
  __shared__ unsigned short lB[2][256 * 32];
  __shared__ float2 red[4][32];
  const int tid = threadIdx.x;
  const int lane = tid & 63, w = tid >> 6;
  const int g = lane >> 4, lr = lane & 15;
  const int m0 = blockIdx.x * 32;
  fx4 acc[2][4] = {};

  auto STAGE = [&](int buf, int kk) {
    {
      int u = tid & 127;  // duplicated across thread halves (identical data)
      int row = u >> 2, sl = u & 3;
      int c = sl ^ ((row >> 1) & 3);
      __builtin_amdgcn_global_load_lds(GAS(A + (size_t)(m0 + row) * K + kk + c * 8),
                                       LAS(&lA[buf][u * 8]), 16, 0, 0);
    }
#pragma unroll
    for (int r = 0; r < 4; ++r) {
      int u = r * 256 + tid;
      int row = u >> 2, sl = u & 3;
      int c = sl ^ ((row >> 1) & 3);
      __builtin_amdgcn_global_load_lds(GAS(BT + (size_t)row * K + kk + c * 8),
                                       LAS(&lB[buf][u * 8]), 16, 0, 0);
    }
  };

  const int nt = K >> 5;
  STAGE(0, 0);
  STAGE(1, 32);
  for (int t = 0; t < nt; ++t) {
    if (t == nt - 1) WAITVM(0); else WAITVM(5);
    __builtin_amdgcn_s_barrier();
    const int buf = t & 1;
    bx8 af[2], bq[4];
#pragma unroll
    for (int i = 0; i < 2; ++i) {
      int row = i * 16 + lr;
      af[i] = *(const bx8*)&lA[buf][row * 32 + (g ^ ((row >> 1) & 3)) * 8];
    }
#pragma unroll
    for (int j = 0; j < 4; ++j) {
      int col = w * 64 + j * 16 + lr;
      bq[j] = *(const bx8*)&lB[buf][col * 32 + (g ^ ((col >> 1) & 3)) * 8];
    }
    WAITLG0();
    __builtin_amdgcn_s_barrier();
    if (t + 2 < nt) STAGE(buf, (t + 2) * 32);
#pragma unroll
    for (int i = 0; i < 2; ++i)
#pragma unroll
      for (int j = 0; j < 4; ++j)
        acc[i][j] = __builtin_amdgcn_mfma_f32_16x16x32_bf16(bq[j], af[i], acc[i][j], 0, 0, 0);
  }

  // epilogue: v in acc, RMW x_res, per-row LN reduce
  float s[2] = {0.f, 0.f}, q[2] = {0.f, 0.f};
#pragma unroll
  for (int i = 0; i < 2; ++i) {
    const int m = m0 + i * 16 + lr;
#pragma unroll
    for (int j = 0; j < 4; ++j) {
      const int nc = w * 64 + j * 16 + g * 4;
      const float4 bv = *(const float4*)(bvec + nc);
      float v0 = acc[i][j][0] + bv.x, v1 = acc[i][j][1] + bv.y;
      float v2 = acc[i][j][2] + bv.z, v3 = acc[i][j][3] + bv.w;
      if constexpr (EP == 2) {
        const float4 cb = *(const float4*)(cbias + (size_t)(m & 255) * 256 + nc);
        v0 += cb.x; v1 += cb.y; v2 += cb.z; v3 += cb.w;
      }
      float4* rp = (float4*)(resid + (size_t)m * 256 + nc);
      float4 old = *rp;
      v0 += old.x; v1 += old.y; v2 += old.z; v3 += old.w;
      *rp = make_float4(v0, v1, v2, v3);
      acc[i][j][0] = v0; acc[i][j][1] = v1; acc[i][j][2] = v2; acc[i][j][3] = v3;
      s[i] += v0 + v1 + v2 + v3;
      q[i] += v0 * v0 + v1 * v1 + v2 * v2 + v3 * v3;
    }
  }
#pragma unroll
  for (int i = 0; i < 2; ++i) {
    s[i] += __shfl_xor(s[i], 16); s[i] += __shfl_xor(s[i], 32);
    q[i] += __shfl_xor(q[i], 16); q[i] += __shfl_xor(q[i], 32);
  }
  if (lane < 16) {
#pragma unroll
    for (int i = 0; i < 2; ++i) red[w][i * 16 + lr] = make_float2(s[i], q[i]);
  }
  __syncthreads();
  float mean[2], rs[2];
#pragma unroll
  for (int i = 0; i < 2; ++i) {
    float2 r0 = red[0][i * 16 + lr], r1 = red[1][i * 16 + lr];
    float2 r2 = red[2][i * 16 + lr], r3 = red[3][i * 16 + lr];
    float S = r0.x + r1.x + r2.x + r3.x;
    float Q = r0.y + r1.y + r2.y + r3.y;
    mean[i] = S * (1.0f / 256.0f);
    rs[i] = rsqrtf(Q * (1.0f / 256.0f) - mean[i] * mean[i] + 1e-5f);
  }
  if constexpr (LNM == 1) {
    if (w == 0 && g == 0) {
#pragma unroll
      for (int i = 0; i < 2; ++i) stats[m0 + i * 16 + lr] = make_float2(mean[i], rs[i]);
    }
  } else {
#pragma unroll
    for (int i = 0; i < 2; ++i) {
      const int m = m0 + i * 16 + lr;
#pragma unroll
      for (int j = 0; j < 4; ++j) {
        const int nc = w * 64 + j * 16 + g * 4;
        const float4 gv = *(const float4*)(lnw + nc);
        const float4 bv2 = *(const float4*)(lnb + nc);
        ushort4 st;
        st.x = f2bf((acc[i][j][0] - mean[i]) * rs[i] * gv.x + bv2.x);
        st.y = f2bf((acc[i][j][1] - mean[i]) * rs[i] * gv.y + bv2.y);
        st.z = f2bf((acc[i][j][2] - mean[i]) * rs[i] * gv.z + bv2.z);
        st.w = f2bf((acc[i][j][3] - mean[i]) * rs[i] * gv.w + bv2.w);
        *(ushort4*)(hn + (size_t)m * 256 + nc) = st;
      }
    }
  }
}

// ---------- fused W2+swiglu BM=64: 4-BUFFER ring, DEPTH-3 prefetch ----------
// Depth-1->2 gave +14% (67.4->58.9us). 80KB LDS keeps 2 blocks/CU (same as 60KB)
// so depth-3 isolates pipeline depth at constant occupancy. Steady vmcnt(15)
// = 3 stages x 5 loads in flight; drain 10 -> 5 -> 0.
__global__ __launch_bounds__(256) void gemm_w2f64_kernel(const unsigned short* __restrict__ A,
                                                         const unsigned short* __restrict__ BT,
                                                         const float* __restrict__ b2,
                                                         unsigned short* __restrict__ gout) {
  __shared__ unsigned short lA[4][64 * 32];
  __shared__ unsigned short lBa[4][128 * 32];
  __shared__ unsigned short lBg[4][128 * 32];
  const int tid = threadIdx.x;
  const int lane = tid & 63, w = tid >> 6;
  const int g = lane >> 4, lr = lane & 15;
  const int m0 = blockIdx.y * 64, n0 = blockIdx.x * 128;
  fx4 aA[4][2] = {}, aG[4][2] = {};

  auto STAGE = [&](int buf, int kk) {
    {
      int u = tid;
      int row = u >> 2, sl = u & 3;
      int c = sl ^ ((row >> 1) & 3);
      __builtin_amdgcn_global_load_lds(GAS(A + (size_t)(m0 + row) * 1024 + kk + c * 8),
                                       LAS(&lA[buf][u * 8]), 16, 0, 0);
    }
#pragma unroll
    for (int r = 0; r < 2; ++r) {
      int u = r * 256 + tid;
      int row = u >> 2, sl = u & 3;
      int c = sl ^ ((row >> 1) & 3);
      __builtin_amdgcn_global_load_lds(GAS(BT + (size_t)(n0 + row) * 1024 + kk + c * 8),
                                       LAS(&lBa[buf][u * 8]), 16, 0, 0);
      __builtin_amdgcn_global_load_lds(GAS(BT + (size_t)(256 + n0 + row) * 1024 + kk + c * 8),
                                       LAS(&lBg[buf][u * 8]), 16, 0, 0);
    }
  };

  STAGE(0, 0);
  STAGE(1, 32);
  STAGE(2, 64);
  STAGE(3, 96);
  int buf = 0;
  for (int t = 0; t < 32; ++t) {
    if (t < 29) WAITVM(15);
    else if (t == 29) WAITVM(10);
    else if (t == 30) WAITVM(5);
    else WAITVM(0);
    __builtin_amdgcn_s_barrier();
    bx8 af[4], ba[2], bg[2];
#pragma unroll
    for (int i = 0; i < 4; ++i) {
      int row = i * 16 + lr;
      af[i] = *(const bx8*)&lA[buf][row * 32 + (g ^ ((row >> 1) & 3)) * 8];
    }
#pragma unroll
    for (int j = 0; j < 2; ++j) {
      int col = w * 32 + j * 16 + lr;
      int sw = (g ^ ((col >> 1) & 3)) * 8;
      ba[j] = *(const bx8*)&lBa[buf][col * 32 + sw];
      bg[j] = *(const bx8*)&lBg[buf][col * 32 + sw];
    }
    WAITLG0();
    __builtin_amdgcn_s_barrier();
    if (t + 4 < 32) STAGE(buf, (t + 4) * 32);  // reuse just-consumed buffer
#pragma unroll
    for (int i = 0; i < 4; ++i)
#pragma unroll
      for (int j = 0; j < 2; ++j) {
        aA[i][j] = __builtin_amdgcn_mfma_f32_16x16x32_bf16(ba[j], af[i], aA[i][j], 0, 0, 0);
        aG[i][j] = __builtin_amdgcn_mfma_f32_16x16x32_bf16(bg[j], af[i], aG[i][j], 0, 0, 0);
      }
    buf = (buf + 1) & 3;
  }

#pragma unroll
  for (int i = 0; i < 4; ++i) {
    const int m = m0 + i * 16 + lr;
#pragma unroll
    for (int j = 0; j < 2; ++j) {
      const int nc = n0 + w * 32 + j * 16 + g * 4;
      const float4 bva = *(const float4*)(b2 + nc);
      const float4 bvg = *(const float4*)(b2 + 256 + nc);
      float a0 = aA[i][j][0] + bva.x, a1 = aA[i][j][1] + bva.y;
      float a2 = aA[i][j][2] + bva.z, a3 = aA[i][j][3] + bva.w;
      float g0 = aG[i][j][0] + bvg.x, g1 = aG[i][j][1] + bvg.y;
      float g2 = aG[i][j][2] + bvg.z, g3 = aG[i][j][3] + bvg.w;
      ushort4 st;
      st.x = f2bf(a0 / (1.0f + __expf(-g0)));
      st.y = f2bf(a1 / (1.0f + __expf(-g1)));
      st.z = f2bf(a2 / (1.0f + __expf(-g2)));
      st.w = f2bf(a3 / (1.0f + __expf(-g3)));
      *(ushort4*)(gout + (size_t)m * 256 + nc) = st;
    }
  }
}

// ---------- fused attention (round-14 proven form: 56us): one block per (b,h) ----------
// Round-15 lesson: splitting q-tiles across blocks re-staged K/V from HBM
// (FETCH 43->116MB, qkv buffer doesn't fit L2) — net loss. Keep 4 its/block.
__global__ __launch_bounds__(256) void attn_kernel(const unsigned short* __restrict__ qkv,
                                                   const unsigned short* __restrict__ vT,
                                                   const float* __restrict__ cbias,
                                                   unsigned short* __restrict__ attnb) {
  __shared__ unsigned short Kl[256 * 32];
  __shared__ unsigned short Vl[1024 * 8];
  const int bh = blockIdx.x, b = bh >> 3, h = bh & 7;
  const int tid = threadIdx.x, lane = tid & 63, w = tid >> 6;
  const int g = lane >> 4, lr = lane & 15;
  const unsigned short* qb_ = qkv + (size_t)b * 196608;
  const unsigned short* vTb = vT + (size_t)bh * 8192;
#pragma unroll
  for (int r = 0; r < 4; ++r) {
    int u = r * 256 + tid;
    int s = u >> 2, sl = u & 3;
    int c = sl ^ ((s >> 1) & 3);
    __builtin_amdgcn_global_load_lds(GAS(qb_ + (size_t)s * 768 + 256 + h * 32 + c * 8),
                                     LAS(&Kl[u * 8]), 16, 0, 0);
    __builtin_amdgcn_global_load_lds(GAS(vTb + u * 8), LAS(&Vl[u * 8]), 16, 0, 0);
  }
  asm volatile("s_waitcnt vmcnt(0)" ::: "memory");
  __syncthreads();
  const float scale = 0.17677669529663689f;
  const fx4 zero = {0.f, 0.f, 0.f, 0.f};
#pragma unroll 1
  for (int it = 0; it < 4; ++it) {
    const int t = it * 64 + w * 16 + lr;
    bx8 qf = *(const bx8*)(qb_ + (size_t)t * 768 + h * 32 + g * 8);
    float p[16][4];
    float mx = -1e30f;
#pragma unroll
    for (int n = 0; n < 16; ++n) {
      int sr = n * 16 + lr;
      bx8 kf = *(const bx8*)&Kl[sr * 32 + (g ^ ((sr >> 1) & 3)) * 8];
      fx4 sc = __builtin_amdgcn_mfma_f32_16x16x32_bf16(kf, qf, zero, 0, 0, 0);
      const float4 cb = *(const float4*)(cbias + (size_t)t * 256 + n * 16 + g * 4);
      p[n][0] = sc[0] * scale + cb.x;
      p[n][1] = sc[1] * scale + cb.y;
      p[n][2] = sc[2] * scale + cb.z;
      p[n][3] = sc[3] * scale + cb.w;
      mx = fmaxf(mx, fmaxf(fmaxf(p[n][0], p[n][1]), fmaxf(p[n][2], p[n][3])));
    }
    mx = fmaxf(mx, __shfl_xor(mx, 16));
    mx = fmaxf(mx, __shfl_xor(mx, 32));
    float sum = 0.f;
    bx8 bq[8];
#pragma unroll
    for (int c = 0; c < 8; ++c) {
      union { bx8 v; unsigned short u[8]; } pk;
#pragma unroll
      for (int jj = 0; jj < 8; ++jj) {
        float e = __expf(p[2 * c + (jj >> 2)][jj & 3] - mx);
        sum += e;
        pk.u[jj] = f2bf(e);
      }
      bq[c] = pk.v;
    }
    sum += __shfl_xor(sum, 16);
    sum += __shfl_xor(sum, 32);
    const float inv = 1.0f / sum;
    fx4 oa0 = zero, oa1 = zero;
#pragma unroll
    for (int c = 0; c < 8; ++c) {
      int u0 = c * 128 + g * 32 + lr;
      int u0p = (u0 & ~7) | ((u0 & 7) ^ ((u0 >> 3) & 7));
      bx8 vf0 = *(const bx8*)&Vl[u0p * 8];
      oa0 = __builtin_amdgcn_mfma_f32_16x16x32_bf16(vf0, bq[c], oa0, 0, 0, 0);
      int u1 = u0 + 16;
      int u1p = (u1 & ~7) | ((u1 & 7) ^ ((u1 >> 3) & 7));
      bx8 vf1 = *(const bx8*)&Vl[u1p * 8];
      oa1 = __builtin_amdgcn_mfma_f32_16x16x32_bf16(vf1, bq[c], oa1, 0, 0, 0);
    }
    ushort4 o0, o1;
    o0.x = f2bf(oa0[0] * inv); o0.y = f2bf(oa0[1] * inv);
    o0.z = f2bf(oa0[2] * inv); o0.w = f2bf(oa0[3] * inv);
    o1.x = f2bf(oa1[0] * inv); o1.y = f2bf(oa1[1] * inv);
    o1.z = f2bf(oa1[2] * inv); o1.w = f2bf(oa1[3] * inv);
    unsigned short* orow = attnb + (size_t)(b * 256 + t) * 256 + h * 32;
    *(ushort4*)(orow + 4 * g) = o0;
    *(ushort4*)(orow + 16 + 4 * g) = o1;
  }
}

// ---------- orchestration ----------
extern "C" void kernel_launch(void* const* d_in, const int* in_sizes, int n_in,
                              void* d_out, int out_size, void* d_ws, size_t ws_size,
                              hipStream_t stream) {
  (void)in_sizes; (void)n_in; (void)out_size; (void)ws_size;
  const float* x     = (const float*)d_in[0];
  const float* cemb  = (const float*)d_in[1];
  const float* pemb  = (const float*)d_in[2];
  const float* cbias = (const float*)d_in[3];
  const float* ln1g  = (const float*)d_in[4];
  const float* ln1b  = (const float*)d_in[5];
  const float* qkvw  = (const float*)d_in[6];
  const float* qkvb  = (const float*)d_in[7];
  const float* outw  = (const float*)d_in[8];
  const float* outbv = (const float*)d_in[9];
  const float* ln2g  = (const float*)d_in[10];
  const float* ln2b  = (const float*)d_in[11];
  const float* w1    = (const float*)d_in[12];
  const float* b1    = (const float*)d_in[13];
  const float* w2    = (const float*)d_in[14];
  const float* b2    = (const float*)d_in[15];
  const float* w3    = (const float*)d_in[16];
  const float* b3    = (const float*)d_in[17];
  const float* fing  = (const float*)d_in[18];
  const float* finb  = (const float*)d_in[19];

  char* ws = (char*)d_ws;
  float* x_res = (float*)(ws);
  unsigned short* hn   = (unsigned short*)(ws + 33554432);
  unsigned short* big  = (unsigned short*)(ws + 50331648);
  unsigned short* vT   = (unsigned short*)(ws + 100663296);
  unsigned short* wT   = (unsigned short*)(ws + 117440512);
  float2* stats = (float2*)(ws + 130809856);
  float* part  = (float*)big;  // mean partials: big dead by then

  unsigned short* qkvwT = wT;                 // 6*768*256
  unsigned short* outwT = wT + 1179648;       // 6*256*256
  unsigned short* w1T   = wT + 1572864;       // 6*1024*256
  unsigned short* w2T   = wT + 3145728;       // 6*512*1024
  unsigned short* w3T   = wT + 6291456;       // 6*256*256

  wtrans_kernel<<<dim3(12, 4, 6), 256, 0, stream>>>(qkvw, qkvwT, 256, 768);
  wtrans_kernel<<<dim3(4, 4, 6), 256, 0, stream>>>(outw, outwT, 256, 256);
  wtrans_kernel<<<dim3(16, 4, 6), 256, 0, stream>>>(w1, w1T, 256, 1024);
  wtrans_kernel<<<dim3(8, 16, 6), 256, 0, stream>>>(w2, w2T, 1024, 512);
  wtrans_kernel<<<dim3(4, 4, 6), 256, 0, stream>>>(w3, w3T, 256, 256);
  embed_ln_kernel<<<8192, 256, 0, stream>>>((const float4*)x, (const float4*)cemb,
                                            (const float4*)pemb, ln1g, ln1b,
                                            (float4*)x_res, hn);
  for (int l = 0; l < 6; ++l) {
    gemm_kernel<4><<<dim3(6, 256), 256, 0, stream>>>(hn, qkvwT + (size_t)l * 196608,
                                                     qkvb + l * 768, (float*)vT, big,
                                                     768, 256);
    attn_kernel<<<1024, 256, 0, stream>>>(big, vT, cbias, hn);
    gemm_ln_kernel<2, 0><<<1024, 256, 0, stream>>>(hn, outwT + (size_t)l * 65536,
                                                   outbv + l * 256, cbias, x_res,
                                                   ln2g + l * 256, ln2b + l * 256, hn,
                                                   nullptr, 256);
    gemm_kernel<1><<<dim3(8, 256), 256, 0, stream>>>(hn, w1T + (size_t)l * 262144,
                                                     b1 + l * 1024, nullptr, big,
                                                     1024, 256);
    gemm_w2f64_kernel<<<dim3(2, 512), 256, 0, stream>>>(big, w2T + (size_t)l * 524288,
                                                        b2 + l * 512, hn);
    if (l < 5) {
      gemm_ln_kernel<3, 0><<<1024, 256, 0, stream>>>(hn, w3T + (size_t)l * 65536,
                                                     b3 + l * 256, nullptr, x_res,
                                                     ln1g + (l + 1) * 256,
                                                     ln1b + (l + 1) * 256, hn,
                                                     nullptr, 256);
    } else {
      gemm_ln_kernel<3, 1><<<1024, 256, 0, stream>>>(hn, w3T + (size_t)l * 65536,
                                                     b3 + l * 256, nullptr, x_res,
                                                     nullptr, nullptr, nullptr,
                                                     stats, 256);
    }
  }
  mean_part_kernel<<<dim3(128, 2), 256, 0, stream>>>(x_res, stats, part);
  mean_fin_kernel<<<128, 256, 0, stream>>>(part, fing, finb, (float*)d_out);
}

// Round 18
// 1430.337 us; speedup vs baseline: 1.0848x; 1.0415x over previous
//
#include <hip/hip_runtime.h>

// ---------- types / helpers ----------
typedef __bf16 bx8 __attribute__((ext_vector_type(8)));
typedef float fx4 __attribute__((ext_vector_type(4)));

#define GAS(p) ((const __attribute__((address_space(1))) void*)(const void*)(p))
#define LAS(p) ((__attribute__((address_space(3))) void*)(void*)(p))
#define WAITVM(n) do { asm volatile("s_waitcnt vmcnt(" #n ")" ::: "memory"); \
                       __builtin_amdgcn_sched_barrier(0); } while (0)
#define WAITLG0() do { asm volatile("s_waitcnt lgkmcnt(0)" ::: "memory"); \
                       __builtin_amdgcn_sched_barrier(0); } while (0)

// per-head tensor size: 1024 bh * 8192 shorts = 8388608 SHORTS (16.7MB).
// Round-17 bug: used 16777216 (the BYTE count) as a short stride -> K region
// overlapped vT and corrupted V. Stride must be 8388608 shorts.
#define QKV_REGION 8388608

__device__ __forceinline__ unsigned short f2bf(float f) {
  return __builtin_bit_cast(unsigned short, (__bf16)f);  // native RTNE
}

// ---------- tiled weight transpose + bf16 cast: dst[l][n][k] = (bf16)src[l][k][n] ----------
__global__ __launch_bounds__(256) void wtrans_kernel(const float* __restrict__ src,
                                                     unsigned short* __restrict__ dst,
                                                     int K, int N) {
  __shared__ unsigned short t[64][68];
  const int l = blockIdx.z;
  const float* s = src + (size_t)l * K * N;
  unsigned short* d = dst + (size_t)l * N * K;
  const int n0 = blockIdx.x * 64, k0 = blockIdx.y * 64;
  const int tx = threadIdx.x & 63, ty = threadIdx.x >> 6;
#pragma unroll
  for (int r = 0; r < 64; r += 4)
    t[tx][ty + r] = f2bf(s[(size_t)(k0 + ty + r) * N + n0 + tx]);
  __syncthreads();
#pragma unroll
  for (int r = 0; r < 64; r += 4)
    d[(size_t)(n0 + ty + r) * K + k0 + tx] = t[ty + r][tx];
}

// ---------- fused embed + ln1(layer0): one wave per row ----------
__global__ __launch_bounds__(256) void embed_ln_kernel(const float4* __restrict__ x,
                                                       const float4* __restrict__ ce,
                                                       const float4* __restrict__ pe,
                                                       const float* __restrict__ gw,
                                                       const float* __restrict__ bw,
                                                       float4* __restrict__ xres,
                                                       unsigned short* __restrict__ hn) {
  const int row = blockIdx.x * 4 + (threadIdx.x >> 6);
  const int lane = threadIdx.x & 63;
  const int t = row & 255;
  const size_t idx = (size_t)row * 64 + lane;
  float4 a = x[idx], b = ce[t * 64 + lane], p = pe[(t + 1) * 64 + lane];
  float4 v = make_float4(a.x + b.x + p.x, a.y + b.y + p.y, a.z + b.z + p.z, a.w + b.w + p.w);
  xres[idx] = v;
  float s = v.x + v.y + v.z + v.w;
  float q = v.x * v.x + v.y * v.y + v.z * v.z + v.w * v.w;
#pragma unroll
  for (int off = 1; off < 64; off <<= 1) {
    s += __shfl_xor(s, off);
    q += __shfl_xor(q, off);
  }
  float mean = s * (1.0f / 256.0f);
  float rs = rsqrtf(q * (1.0f / 256.0f) - mean * mean + 1e-5f);
  float4 gv = *(const float4*)(gw + lane * 4);
  float4 bv = *(const float4*)(bw + lane * 4);
  ushort4 o;
  o.x = f2bf((v.x - mean) * rs * gv.x + bv.x);
  o.y = f2bf((v.y - mean) * rs * gv.y + bv.y);
  o.z = f2bf((v.z - mean) * rs * gv.z + bv.z);
  o.w = f2bf((v.w - mean) * rs * gv.w + bv.w);
  *(ushort4*)(hn + (size_t)row * 256 + lane * 4) = o;
}

// ---------- final mean, two-stage ----------
__global__ __launch_bounds__(256) void mean_part_kernel(const float* __restrict__ x,
                                                        const float2* __restrict__ stats,
                                                        float* __restrict__ part) {
  int b = blockIdx.x, half = blockIdx.y, c = threadIdx.x;
  const float* xb = x + (size_t)b * 65536 + half * 32768;
  const float2* st = stats + b * 256 + half * 128;
  float acc = 0.f;
#pragma unroll 4
  for (int t = 0; t < 128; ++t) {
    float2 s = st[t];
    acc += (xb[t * 256 + c] - s.x) * s.y;
  }
  part[(size_t)(b * 2 + half) * 256 + c] = acc;
}
__global__ __launch_bounds__(256) void mean_fin_kernel(const float* __restrict__ part,
                                                       const float* __restrict__ fg,
                                                       const float* __restrict__ fb,
                                                       float* __restrict__ out) {
  int b = blockIdx.x, c = threadIdx.x;
  out[b * 256 + c] =
      (part[(size_t)(2 * b) * 256 + c] + part[(size_t)(2 * b + 1) * 256 + c]) *
          (1.0f / 256.0f) * fg[c] + fb[c];
}

// ---------- GEMM 128x128: 3-BUFFER ring, DEPTH-2 prefetch (4 loads/stage) ----------
// EP 1: out_bf16 = gelu_exact(acc + bvec)
// EP 4: qkv epilogue -> per-head-contiguous tensors:
//       nc<256: qT[bh][s][d]; 256<=nc<512: kT = qT + QKV_REGION; nc>=512: vT image.
template <int EP>
__global__ __launch_bounds__(256) void gemm_kernel(const unsigned short* __restrict__ A,
                                                   const unsigned short* __restrict__ BT,
                                                   const float* __restrict__ bvec,
                                                   float* __restrict__ resid,
                                                   unsigned short* __restrict__ outb,
                                                   int N, int K) {
  __shared__ unsigned short lA[3][128 * 32];
  __shared__ unsigned short lB[3][128 * 32];
  const int tid = threadIdx.x;
  const int lane = tid & 63, w = tid >> 6;
  const int wr = w >> 1, wc = w & 1;
  const int g = lane >> 4, lr = lane & 15;
  const int m0 = blockIdx.y * 128, n0 = blockIdx.x * 128;
  fx4 acc[4][4] = {};

  auto STAGE = [&](int buf, int kk) {
#pragma unroll
    for (int r = 0; r < 2; ++r) {
      int u = r * 256 + tid;
      int row = u >> 2, sl = u & 3;
      int c = sl ^ ((row >> 1) & 3);
      __builtin_amdgcn_global_load_lds(GAS(A + (size_t)(m0 + row) * K + kk + c * 8),
                                       LAS(&lA[buf][u * 8]), 16, 0, 0);
      __builtin_amdgcn_global_load_lds(GAS(BT + (size_t)(n0 + row) * K + kk + c * 8),
                                       LAS(&lB[buf][u * 8]), 16, 0, 0);
    }
  };

  const int nt = K >> 5;
  STAGE(0, 0);
  STAGE(1, 32);
  STAGE(2, 64);
  int buf = 0;
  for (int t = 0; t < nt; ++t) {
    if (t < nt - 2) WAITVM(8); else if (t == nt - 2) WAITVM(4); else WAITVM(0);
    __builtin_amdgcn_s_barrier();
    bx8 af[4], bq[4];
#pragma unroll
    for (int i = 0; i < 4; ++i) {
      int row = wr * 64 + i * 16 + lr;
      af[i] = *(const bx8*)&lA[buf][row * 32 + (g ^ ((row >> 1) & 3)) * 8];
      int col = wc * 64 + i * 16 + lr;
      bq[i] = *(const bx8*)&lB[buf][col * 32 + (g ^ ((col >> 1) & 3)) * 8];
    }
    WAITLG0();
    __builtin_amdgcn_s_barrier();
    if (t + 3 < nt) STAGE(buf, (t + 3) * 32);
#pragma unroll
    for (int i = 0; i < 4; ++i)
#pragma unroll
      for (int j = 0; j < 4; ++j)
        acc[i][j] = __builtin_amdgcn_mfma_f32_16x16x32_bf16(bq[j], af[i], acc[i][j], 0, 0, 0);
    buf = (buf == 2) ? 0 : buf + 1;
  }

#pragma unroll
  for (int i = 0; i < 4; ++i) {
    const int m = m0 + wr * 64 + i * 16 + lr;
#pragma unroll
    for (int j = 0; j < 4; ++j) {
      const int nc = n0 + wc * 64 + j * 16 + g * 4;
      const float4 bv = *(const float4*)(bvec + nc);
      float v0 = acc[i][j][0] + bv.x, v1 = acc[i][j][1] + bv.y;
      float v2 = acc[i][j][2] + bv.z, v3 = acc[i][j][3] + bv.w;
      if constexpr (EP == 1) {
        v0 = 0.5f * v0 * (1.0f + erff(v0 * 0.70710678118654752f));
        v1 = 0.5f * v1 * (1.0f + erff(v1 * 0.70710678118654752f));
        v2 = 0.5f * v2 * (1.0f + erff(v2 * 0.70710678118654752f));
        v3 = 0.5f * v3 * (1.0f + erff(v3 * 0.70710678118654752f));
      }
      if constexpr (EP == 1) {
        ushort4 st;
        st.x = f2bf(v0); st.y = f2bf(v1); st.z = f2bf(v2); st.w = f2bf(v3);
        *(ushort4*)(outb + (size_t)m * N + nc) = st;
      } else {  // EP 4
        const int s = m & 255, b = m >> 8;
        if (nc < 512) {
          ushort4 st;
          st.x = f2bf(v0); st.y = f2bf(v1); st.z = f2bf(v2); st.w = f2bf(v3);
          const int region = nc >> 8;        // 0 = q, 1 = k
          const int h = (nc >> 5) & 7, d0 = nc & 31;
          *(ushort4*)(outb + (size_t)region * QKV_REGION +
                      (size_t)(b * 8 + h) * 8192 + s * 32 + d0) = st;
        } else {
          unsigned short* vTp = (unsigned short*)resid;
          const int hv = nc - 512;
          const int h = hv >> 5, d0 = hv & 31;
          const int jj = (s & 3) + 4 * ((s >> 4) & 1);
          const int ub = (s >> 5) * 128 + ((s >> 2) & 3) * 32 + d0;
          unsigned short* base = vTp + (size_t)(b * 8 + h) * 8192;
          const float vv[4] = {v0, v1, v2, v3};
#pragma unroll
          for (int r = 0; r < 4; ++r) {
            int u = ub + r;
            int up = (u & ~7) | ((u & 7) ^ ((u >> 3) & 7));
            base[up * 8 + jj] = f2bf(vv[r]);
          }
        }
      }
    }
  }
}

// ---------- GEMM 32x256 + residual + FUSED LN (2-buffer, 4 blocks/CU) ----------
// EP 2: v = acc + bvec + col_bias[m&255][nc] + x_res   (proj path)
// EP 3: v = acc + bvec + x_res                          (W3 path)
// LNM 0: hn = (v-mean)*rs*lnw+lnb; LNM 1: stats[m]=(mean,rs).
template <int EP, int LNM>
__global__ __launch_bounds__(256) void gemm_ln_kernel(const unsigned short* __restrict__ A,
                                                      const unsigned short* __restrict__ BT,
                                                      const float* __restrict__ bvec,
                                                      const float* __restrict__ cbias,
                                                      float* __restrict__ resid,
                                                      const float* __restrict__ lnw,
                                                      const float* __restrict__ lnb,
                                                      unsigned short* __restrict__ hn,
                                                      float2* __restrict__ stats,
                                                      int K) {
  __shared__ unsigned short lA[2][32 * 32];
  __shared__ unsigned short lB[2][256 * 32];
  __shared__ float2 red[4][32];
  const int tid = threadIdx.x;
  const int lane = tid & 63, w = tid >> 6;
  const int g = lane >> 4, lr = lane & 15;
  const int m0 = blockIdx.x * 32;
  fx4 acc[2][4] = {};

  auto STAGE = [&](int buf, int kk) {
    {
      int u = tid & 127;  // duplicated across thread halves (identical data)
      int row = u >> 2, sl = u & 3;
      int c = sl ^ ((row >> 1) & 3);
      __builtin_amdgcn_global_load_lds(GAS(A + (size_t)(m0 + row) * K + kk + c * 8),
                                       LAS(&lA[buf][u * 8]), 16, 0, 0);
    }
#pragma unroll
    for (int r = 0; r < 4; ++r) {
      int u = r * 256 + tid;
      int row = u >> 2, sl = u & 3;
      int c = sl ^ ((row >> 1) & 3);
      __builtin_amdgcn_global_load_lds(GAS(BT + (size_t)row * K + kk + c * 8),
                                       LAS(&lB[buf][u * 8]), 16, 0, 0);
    }
  };

  const int nt = K >> 5;
  STAGE(0, 0);
  STAGE(1, 32);
  for (int t = 0; t < nt; ++t) {
    if (t == nt - 1) WAITVM(0); else WAITVM(5);
    __builtin_amdgcn_s_barrier();
    const int buf = t & 1;
    bx8 af[2], bq[4];
#pragma unroll
    for (int i = 0; i < 2; ++i) {
      int row = i * 16 + lr;
      af[i] = *(const bx8*)&lA[buf][row * 32 + (g ^ ((row >> 1) & 3)) * 8];
    }
#pragma unroll
    for (int j = 0; j < 4; ++j) {
      int col = w * 64 + j * 16 + lr;
      bq[j] = *(const bx8*)&lB[buf][col * 32 + (g ^ ((col >> 1) & 3)) * 8];
    }
    WAITLG0();
    __builtin_amdgcn_s_barrier();
    if (t + 2 < nt) STAGE(buf, (t + 2) * 32);
#pragma unroll
    for (int i = 0; i < 2; ++i)
#pragma unroll
      for (int j = 0; j < 4; ++j)
        acc[i][j] = __builtin_amdgcn_mfma_f32_16x16x32_bf16(bq[j], af[i], acc[i][j], 0, 0, 0);
  }

  float s[2] = {0.f, 0.f}, q[2] = {0.f, 0.f};
#pragma unroll
  for (int i = 0; i < 2; ++i) {
    const int m = m0 + i * 16 + lr;
#pragma unroll
    for (int j = 0; j < 4; ++j) {
      const int nc = w * 64 + j * 16 + g * 4;
      const float4 bv = *(const float4*)(bvec + nc);
      float v0 = acc[i][j][0] + bv.x, v1 = acc[i][j][1] + bv.y;
      float v2 = acc[i][j][2] + bv.z, v3 = acc[i][j][3] + bv.w;
      if constexpr (EP == 2) {
        const float4 cb = *(const float4*)(cbias + (size_t)(m & 255) * 256 + nc);
        v0 += cb.x; v1 += cb.y; v2 += cb.z; v3 += cb.w;
      }
      float4* rp = (float4*)(resid + (size_t)m * 256 + nc);
      float4 old = *rp;
      v0 += old.x; v1 += old.y; v2 += old.z; v3 += old.w;
      *rp = make_float4(v0, v1, v2, v3);
      acc[i][j][0] = v0; acc[i][j][1] = v1; acc[i][j][2] = v2; acc[i][j][3] = v3;
      s[i] += v0 + v1 + v2 + v3;
      q[i] += v0 * v0 + v1 * v1 + v2 * v2 + v3 * v3;
    }
  }
#pragma unroll
  for (int i = 0; i < 2; ++i) {
    s[i] += __shfl_xor(s[i], 16); s[i] += __shfl_xor(s[i], 32);
    q[i] += __shfl_xor(q[i], 16); q[i] += __shfl_xor(q[i], 32);
  }
  if (lane < 16) {
#pragma unroll
    for (int i = 0; i < 2; ++i) red[w][i * 16 + lr] = make_float2(s[i], q[i]);
  }
  __syncthreads();
  float mean[2], rs[2];
#pragma unroll
  for (int i = 0; i < 2; ++i) {
    float2 r0 = red[0][i * 16 + lr], r1 = red[1][i * 16 + lr];
    float2 r2 = red[2][i * 16 + lr], r3 = red[3][i * 16 + lr];
    float S = r0.x + r1.x + r2.x + r3.x;
    float Q = r0.y + r1.y + r2.y + r3.y;
    mean[i] = S * (1.0f / 256.0f);
    rs[i] = rsqrtf(Q * (1.0f / 256.0f) - mean[i] * mean[i] + 1e-5f);
  }
  if constexpr (LNM == 1) {
    if (w == 0 && g == 0) {
#pragma unroll
      for (int i = 0; i < 2; ++i) stats[m0 + i * 16 + lr] = make_float2(mean[i], rs[i]);
    }
  } else {
#pragma unroll
    for (int i = 0; i < 2; ++i) {
      const int m = m0 + i * 16 + lr;
#pragma unroll
      for (int j = 0; j < 4; ++j) {
        const int nc = w * 64 + j * 16 + g * 4;
        const float4 gv = *(const float4*)(lnw + nc);
        const float4 bv2 = *(const float4*)(lnb + nc);
        ushort4 st;
        st.x = f2bf((acc[i][j][0] - mean[i]) * rs[i] * gv.x + bv2.x);
        st.y = f2bf((acc[i][j][1] - mean[i]) * rs[i] * gv.y + bv2.y);
        st.z = f2bf((acc[i][j][2] - mean[i]) * rs[i] * gv.z + bv2.z);
        st.w = f2bf((acc[i][j][3] - mean[i]) * rs[i] * gv.w + bv2.w);
        *(ushort4*)(hn + (size_t)m * 256 + nc) = st;
      }
    }
  }
}

// ---------- fused W2+swiglu BM=64: 3-buffer ring, DEPTH-2 (proven 58.9us) ----------
__global__ __launch_bounds__(256) void gemm_w2f64_kernel(const unsigned short* __restrict__ A,
                                                         const unsigned short* __restrict__ BT,
                                                         const float* __restrict__ b2,
                                                         unsigned short* __restrict__ gout) {
  __shared__ unsigned short lA[3][64 * 32];
  __shared__ unsigned short lBa[3][128 * 32];
  __shared__ unsigned short lBg[3][128 * 32];
  const int tid = threadIdx.x;
  const int lane = tid & 63, w = tid >> 6;
  const int g = lane >> 4, lr = lane & 15;
  const int m0 = blockIdx.y * 64, n0 = blockIdx.x * 128;
  fx4 aA[4][2] = {}, aG[4][2] = {};

  auto STAGE = [&](int buf, int kk) {
    {
      int u = tid;
      int row = u >> 2, sl = u & 3;
      int c = sl ^ ((row >> 1) & 3);
      __builtin_amdgcn_global_load_lds(GAS(A + (size_t)(m0 + row) * 1024 + kk + c * 8),
                                       LAS(&lA[buf][u * 8]), 16, 0, 0);
    }
#pragma unroll
    for (int r = 0; r < 2; ++r) {
      int u = r * 256 + tid;
      int row = u >> 2, sl = u & 3;
      int c = sl ^ ((row >> 1) & 3);
      __builtin_amdgcn_global_load_lds(GAS(BT + (size_t)(n0 + row) * 1024 + kk + c * 8),
                                       LAS(&lBa[buf][u * 8]), 16, 0, 0);
      __builtin_amdgcn_global_load_lds(GAS(BT + (size_t)(256 + n0 + row) * 1024 + kk + c * 8),
                                       LAS(&lBg[buf][u * 8]), 16, 0, 0);
    }
  };

  STAGE(0, 0);
  STAGE(1, 32);
  STAGE(2, 64);
  int buf = 0;
  for (int t = 0; t < 32; ++t) {
    if (t < 30) WAITVM(10); else if (t == 30) WAITVM(5); else WAITVM(0);
    __builtin_amdgcn_s_barrier();
    bx8 af[4], ba[2], bg[2];
#pragma unroll
    for (int i = 0; i < 4; ++i) {
      int row = i * 16 + lr;
      af[i] = *(const bx8*)&lA[buf][row * 32 + (g ^ ((row >> 1) & 3)) * 8];
    }
#pragma unroll
    for (int j = 0; j < 2; ++j) {
      int col = w * 32 + j * 16 + lr;
      int sw = (g ^ ((col >> 1) & 3)) * 8;
      ba[j] = *(const bx8*)&lBa[buf][col * 32 + sw];
      bg[j] = *(const bx8*)&lBg[buf][col * 32 + sw];
    }
    WAITLG0();
    __builtin_amdgcn_s_barrier();
    if (t + 3 < 32) STAGE(buf, (t + 3) * 32);
#pragma unroll
    for (int i = 0; i < 4; ++i)
#pragma unroll
      for (int j = 0; j < 2; ++j) {
        aA[i][j] = __builtin_amdgcn_mfma_f32_16x16x32_bf16(ba[j], af[i], aA[i][j], 0, 0, 0);
        aG[i][j] = __builtin_amdgcn_mfma_f32_16x16x32_bf16(bg[j], af[i], aG[i][j], 0, 0, 0);
      }
    buf = (buf == 2) ? 0 : buf + 1;
  }

#pragma unroll
  for (int i = 0; i < 4; ++i) {
    const int m = m0 + i * 16 + lr;
#pragma unroll
    for (int j = 0; j < 2; ++j) {
      const int nc = n0 + w * 32 + j * 16 + g * 4;
      const float4 bva = *(const float4*)(b2 + nc);
      const float4 bvg = *(const float4*)(b2 + 256 + nc);
      float a0 = aA[i][j][0] + bva.x, a1 = aA[i][j][1] + bva.y;
      float a2 = aA[i][j][2] + bva.z, a3 = aA[i][j][3] + bva.w;
      float g0 = aG[i][j][0] + bvg.x, g1 = aG[i][j][1] + bvg.y;
      float g2 = aG[i][j][2] + bvg.z, g3 = aG[i][j][3] + bvg.w;
      ushort4 st;
      st.x = f2bf(a0 / (1.0f + __expf(-g0)));
      st.y = f2bf(a1 / (1.0f + __expf(-g1)));
      st.z = f2bf(a2 / (1.0f + __expf(-g2)));
      st.w = f2bf(a3 / (1.0f + __expf(-g3)));
      *(ushort4*)(gout + (size_t)m * 256 + nc) = st;
    }
  }
}

// ---------- fused attention v5: coalesced per-head Q/K/V (qT/kT/vT) + setprio ----------
__global__ __launch_bounds__(256) void attn_kernel(const unsigned short* __restrict__ qT,
                                                   const unsigned short* __restrict__ vT,
                                                   const float* __restrict__ cbias,
                                                   unsigned short* __restrict__ attnb) {
  __shared__ unsigned short Kl[256 * 32];
  __shared__ unsigned short Vl[1024 * 8];
  const int bh = blockIdx.x, b = bh >> 3, h = bh & 7;
  const int tid = threadIdx.x, lane = tid & 63, w = tid >> 6;
  const int g = lane >> 4, lr = lane & 15;
  const unsigned short* qTb = qT + (size_t)bh * 8192;
  const unsigned short* kTb = qT + QKV_REGION + (size_t)bh * 8192;
  const unsigned short* vTb = vT + (size_t)bh * 8192;
#pragma unroll
  for (int r = 0; r < 4; ++r) {
    int u = r * 256 + tid;
    int s = u >> 2, sl = u & 3;
    int c = sl ^ ((s >> 1) & 3);
    __builtin_amdgcn_global_load_lds(GAS(kTb + s * 32 + c * 8), LAS(&Kl[u * 8]), 16, 0, 0);
    __builtin_amdgcn_global_load_lds(GAS(vTb + u * 8), LAS(&Vl[u * 8]), 16, 0, 0);
  }
  asm volatile("s_waitcnt vmcnt(0)" ::: "memory");
  __syncthreads();
  const float scale = 0.17677669529663689f;
  const fx4 zero = {0.f, 0.f, 0.f, 0.f};
#pragma unroll 1
  for (int it = 0; it < 4; ++it) {
    const int t = it * 64 + w * 16 + lr;
    bx8 qf = *(const bx8*)(qTb + t * 32 + g * 8);
    float p[16][4];
    float mx = -1e30f;
    __builtin_amdgcn_s_setprio(1);
#pragma unroll
    for (int n = 0; n < 16; ++n) {
      int sr = n * 16 + lr;
      bx8 kf = *(const bx8*)&Kl[sr * 32 + (g ^ ((sr >> 1) & 3)) * 8];
      fx4 sc = __builtin_amdgcn_mfma_f32_16x16x32_bf16(kf, qf, zero, 0, 0, 0);
      const float4 cb = *(const float4*)(cbias + (size_t)t * 256 + n * 16 + g * 4);
      p[n][0] = sc[0] * scale + cb.x;
      p[n][1] = sc[1] * scale + cb.y;
      p[n][2] = sc[2] * scale + cb.z;
      p[n][3] = sc[3] * scale + cb.w;
      mx = fmaxf(mx, fmaxf(fmaxf(p[n][0], p[n][1]), fmaxf(p[n][2], p[n][3])));
    }
    __builtin_amdgcn_s_setprio(0);
    mx = fmaxf(mx, __shfl_xor(mx, 16));
    mx = fmaxf(mx, __shfl_xor(mx, 32));
    float sum = 0.f;
    bx8 bq[8];
#pragma unroll
    for (int c = 0; c < 8; ++c) {
      union { bx8 v; unsigned short u[8]; } pk;
#pragma unroll
      for (int jj = 0; jj < 8; ++jj) {
        float e = __expf(p[2 * c + (jj >> 2)][jj & 3] - mx);
        sum += e;
        pk.u[jj] = f2bf(e);
      }
      bq[c] = pk.v;
    }
    sum += __shfl_xor(sum, 16);
    sum += __shfl_xor(sum, 32);
    const float inv = 1.0f / sum;
    fx4 oa0 = zero, oa1 = zero;
    __builtin_amdgcn_s_setprio(1);
#pragma unroll
    for (int c = 0; c < 8; ++c) {
      int u0 = c * 128 + g * 32 + lr;
      int u0p = (u0 & ~7) | ((u0 & 7) ^ ((u0 >> 3) & 7));
      bx8 vf0 = *(const bx8*)&Vl[u0p * 8];
      oa0 = __builtin_amdgcn_mfma_f32_16x16x32_bf16(vf0, bq[c], oa0, 0, 0, 0);
      int u1 = u0 + 16;
      int u1p = (u1 & ~7) | ((u1 & 7) ^ ((u1 >> 3) & 7));
      bx8 vf1 = *(const bx8*)&Vl[u1p * 8];
      oa1 = __builtin_amdgcn_mfma_f32_16x16x32_bf16(vf1, bq[c], oa1, 0, 0, 0);
    }
    __builtin_amdgcn_s_setprio(0);
    ushort4 o0, o1;
    o0.x = f2bf(oa0[0] * inv); o0.y = f2bf(oa0[1] * inv);
    o0.z = f2bf(oa0[2] * inv); o0.w = f2bf(oa0[3] * inv);
    o1.x = f2bf(oa1[0] * inv); o1.y = f2bf(oa1[1] * inv);
    o1.z = f2bf(oa1[2] * inv); o1.w = f2bf(oa1[3] * inv);
    unsigned short* orow = attnb + (size_t)(b * 256 + t) * 256 + h * 32;
    *(ushort4*)(orow + 4 * g) = o0;
    *(ushort4*)(orow + 16 + 4 * g) = o1;
  }
}

// ---------- orchestration ----------
extern "C" void kernel_launch(void* const* d_in, const int* in_sizes, int n_in,
                              void* d_out, int out_size, void* d_ws, size_t ws_size,
                              hipStream_t stream) {
  (void)in_sizes; (void)n_in; (void)out_size; (void)ws_size;
  const float* x     = (const float*)d_in[0];
  const float* cemb  = (const float*)d_in[1];
  const float* pemb  = (const float*)d_in[2];
  const float* cbias = (const float*)d_in[3];
  const float* ln1g  = (const float*)d_in[4];
  const float* ln1b  = (const float*)d_in[5];
  const float* qkvw  = (const float*)d_in[6];
  const float* qkvb  = (const float*)d_in[7];
  const float* outw  = (const float*)d_in[8];
  const float* outbv = (const float*)d_in[9];
  const float* ln2g  = (const float*)d_in[10];
  const float* ln2b  = (const float*)d_in[11];
  const float* w1    = (const float*)d_in[12];
  const float* b1    = (const float*)d_in[13];
  const float* w2    = (const float*)d_in[14];
  const float* b2    = (const float*)d_in[15];
  const float* w3    = (const float*)d_in[16];
  const float* b3    = (const float*)d_in[17];
  const float* fing  = (const float*)d_in[18];
  const float* finb  = (const float*)d_in[19];

  char* ws = (char*)d_ws;
  // Workspace:
  //  R0 x_res fp32   [0, 33554432)
  //  R1 hn bf16      [33554432, 50331648)
  //  R2 [50331648, 100663296): attn phase qT(16.7MB)+kT(16.7MB)+vT(16.7MB);
  //                            MLP phase u[32768][1024] (64MB, overwrites all)
  //  R3 wT bf16      [117440512, 130809856)
  //  R4 stats        [130809856, 131072000)
  float* x_res = (float*)(ws);
  unsigned short* hn   = (unsigned short*)(ws + 33554432);
  unsigned short* big  = (unsigned short*)(ws + 50331648);   // qT base / u base
  unsigned short* vT   = (unsigned short*)(ws + 83886080);   // qT + 2*QKV_REGION shorts
  unsigned short* wT   = (unsigned short*)(ws + 117440512);
  float2* stats = (float2*)(ws + 130809856);
  float* part  = (float*)big;  // mean partials: big dead by then

  unsigned short* qkvwT = wT;                 // 6*768*256
  unsigned short* outwT = wT + 1179648;       // 6*256*256
  unsigned short* w1T   = wT + 1572864;       // 6*1024*256
  unsigned short* w2T   = wT + 3145728;       // 6*512*1024
  unsigned short* w3T   = wT + 6291456;       // 6*256*256

  wtrans_kernel<<<dim3(12, 4, 6), 256, 0, stream>>>(qkvw, qkvwT, 256, 768);
  wtrans_kernel<<<dim3(4, 4, 6), 256, 0, stream>>>(outw, outwT, 256, 256);
  wtrans_kernel<<<dim3(16, 4, 6), 256, 0, stream>>>(w1, w1T, 256, 1024);
  wtrans_kernel<<<dim3(8, 16, 6), 256, 0, stream>>>(w2, w2T, 1024, 512);
  wtrans_kernel<<<dim3(4, 4, 6), 256, 0, stream>>>(w3, w3T, 256, 256);
  embed_ln_kernel<<<8192, 256, 0, stream>>>((const float4*)x, (const float4*)cemb,
                                            (const float4*)pemb, ln1g, ln1b,
                                            (float4*)x_res, hn);
  for (int l = 0; l < 6; ++l) {
    gemm_kernel<4><<<dim3(6, 256), 256, 0, stream>>>(hn, qkvwT + (size_t)l * 196608,
                                                     qkvb + l * 768, (float*)vT, big,
                                                     768, 256);
    attn_kernel<<<1024, 256, 0, stream>>>(big, vT, cbias, hn);
    gemm_ln_kernel<2, 0><<<1024, 256, 0, stream>>>(hn, outwT + (size_t)l * 65536,
                                                   outbv + l * 256, cbias, x_res,
                                                   ln2g + l * 256, ln2b + l * 256, hn,
                                                   nullptr, 256);
    gemm_kernel<1><<<dim3(8, 256), 256, 0, stream>>>(hn, w1T + (size_t)l * 262144,
                                                     b1 + l * 1024, nullptr, big,
                                                     1024, 256);
    gemm_w2f64_kernel<<<dim3(2, 512), 256, 0, stream>>>(big, w2T + (size_t)l * 524288,
                                                        b2 + l * 512, hn);
    if (l < 5) {
      gemm_ln_kernel<3, 0><<<1024, 256, 0, stream>>>(hn, w3T + (size_t)l * 65536,
                                                     b3 + l * 256, nullptr, x_res,
                                                     ln1g + (l + 1) * 256,
                                                     ln1b + (l + 1) * 256, hn,
                                                     nullptr, 256);
    } else {
      gemm_ln_kernel<3, 1><<<1024, 256, 0, stream>>>(hn, w3T + (size_t)l * 65536,
                                                     b3 + l * 256, nullptr, x_res,
                                                     nullptr, nullptr, nullptr,
                                                     stats, 256);
    }
  }
  mean_part_kernel<<<dim3(128, 2), 256, 0, stream>>>(x_res, stats, part);
  mean_fin_kernel<<<128, 256, 0, stream>>>(part, fing, finb, (float*)d_out);
}

// Round 19
// 1428.126 us; speedup vs baseline: 1.0865x; 1.0015x over previous
//
#include <hip/hip_runtime.h>

// ---------- types / helpers ----------
typedef __bf16 bx8 __attribute__((ext_vector_type(8)));
typedef float fx4 __attribute__((ext_vector_type(4)));

#define GAS(p) ((const __attribute__((address_space(1))) void*)(const void*)(p))
#define LAS(p) ((__attribute__((address_space(3))) void*)(void*)(p))
#define WAITVM(n) do { asm volatile("s_waitcnt vmcnt(" #n ")" ::: "memory"); \
                       __builtin_amdgcn_sched_barrier(0); } while (0)
#define WAITLG0() do { asm volatile("s_waitcnt lgkmcnt(0)" ::: "memory"); \
                       __builtin_amdgcn_sched_barrier(0); } while (0)

// per-head tensor size: 1024 bh * 8192 shorts = 8388608 SHORTS (16.7MB).
#define QKV_REGION 8388608

__device__ __forceinline__ unsigned short f2bf(float f) {
  return __builtin_bit_cast(unsigned short, (__bf16)f);  // native RTNE
}

// ---------- tiled weight transpose + bf16 cast: dst[l][n][k] = (bf16)src[l][k][n] ----------
__global__ __launch_bounds__(256) void wtrans_kernel(const float* __restrict__ src,
                                                     unsigned short* __restrict__ dst,
                                                     int K, int N) {
  __shared__ unsigned short t[64][68];
  const int l = blockIdx.z;
  const float* s = src + (size_t)l * K * N;
  unsigned short* d = dst + (size_t)l * N * K;
  const int n0 = blockIdx.x * 64, k0 = blockIdx.y * 64;
  const int tx = threadIdx.x & 63, ty = threadIdx.x >> 6;
#pragma unroll
  for (int r = 0; r < 64; r += 4)
    t[tx][ty + r] = f2bf(s[(size_t)(k0 + ty + r) * N + n0 + tx]);
  __syncthreads();
#pragma unroll
  for (int r = 0; r < 64; r += 4)
    d[(size_t)(n0 + ty + r) * K + k0 + tx] = t[ty + r][tx];
}

// ---------- fused embed + ln1(layer0): one wave per row ----------
__global__ __launch_bounds__(256) void embed_ln_kernel(const float4* __restrict__ x,
                                                       const float4* __restrict__ ce,
                                                       const float4* __restrict__ pe,
                                                       const float* __restrict__ gw,
                                                       const float* __restrict__ bw,
                                                       float4* __restrict__ xres,
                                                       unsigned short* __restrict__ hn) {
  const int row = blockIdx.x * 4 + (threadIdx.x >> 6);
  const int lane = threadIdx.x & 63;
  const int t = row & 255;
  const size_t idx = (size_t)row * 64 + lane;
  float4 a = x[idx], b = ce[t * 64 + lane], p = pe[(t + 1) * 64 + lane];
  float4 v = make_float4(a.x + b.x + p.x, a.y + b.y + p.y, a.z + b.z + p.z, a.w + b.w + p.w);
  xres[idx] = v;
  float s = v.x + v.y + v.z + v.w;
  float q = v.x * v.x + v.y * v.y + v.z * v.z + v.w * v.w;
#pragma unroll
  for (int off = 1; off < 64; off <<= 1) {
    s += __shfl_xor(s, off);
    q += __shfl_xor(q, off);
  }
  float mean = s * (1.0f / 256.0f);
  float rs = rsqrtf(q * (1.0f / 256.0f) - mean * mean + 1e-5f);
  float4 gv = *(const float4*)(gw + lane * 4);
  float4 bv = *(const float4*)(bw + lane * 4);
  ushort4 o;
  o.x = f2bf((v.x - mean) * rs * gv.x + bv.x);
  o.y = f2bf((v.y - mean) * rs * gv.y + bv.y);
  o.z = f2bf((v.z - mean) * rs * gv.z + bv.z);
  o.w = f2bf((v.w - mean) * rs * gv.w + bv.w);
  *(ushort4*)(hn + (size_t)row * 256 + lane * 4) = o;
}

// ---------- final mean, two-stage ----------
__global__ __launch_bounds__(256) void mean_part_kernel(const float* __restrict__ x,
                                                        const float2* __restrict__ stats,
                                                        float* __restrict__ part) {
  int b = blockIdx.x, half = blockIdx.y, c = threadIdx.x;
  const float* xb = x + (size_t)b * 65536 + half * 32768;
  const float2* st = stats + b * 256 + half * 128;
  float acc = 0.f;
#pragma unroll 4
  for (int t = 0; t < 128; ++t) {
    float2 s = st[t];
    acc += (xb[t * 256 + c] - s.x) * s.y;
  }
  part[(size_t)(b * 2 + half) * 256 + c] = acc;
}
__global__ __launch_bounds__(256) void mean_fin_kernel(const float* __restrict__ part,
                                                       const float* __restrict__ fg,
                                                       const float* __restrict__ fb,
                                                       float* __restrict__ out) {
  int b = blockIdx.x, c = threadIdx.x;
  out[b * 256 + c] =
      (part[(size_t)(2 * b) * 256 + c] + part[(size_t)(2 * b + 1) * 256 + c]) *
          (1.0f / 256.0f) * fg[c] + fb[c];
}

// ---------- GEMM 128x128: 3-BUFFER ring, DEPTH-2 prefetch (4 loads/stage) ----------
// EP 1: out_bf16 = gelu_exact(acc + bvec)
// EP 4: qkv epilogue -> per-head-contiguous tensors:
//       nc<256: qT[bh][s][d]; 256<=nc<512: kT = qT + QKV_REGION; nc>=512: vT image.
template <int EP>
__global__ __launch_bounds__(256) void gemm_kernel(const unsigned short* __restrict__ A,
                                                   const unsigned short* __restrict__ BT,
                                                   const float* __restrict__ bvec,
                                                   float* __restrict__ resid,
                                                   unsigned short* __restrict__ outb,
                                                   int N, int K) {
  __shared__ unsigned short lA[3][128 * 32];
  __shared__ unsigned short lB[3][128 * 32];
  const int tid = threadIdx.x;
  const int lane = tid & 63, w = tid >> 6;
  const int wr = w >> 1, wc = w & 1;
  const int g = lane >> 4, lr = lane & 15;
  const int m0 = blockIdx.y * 128, n0 = blockIdx.x * 128;
  fx4 acc[4][4] = {};

  auto STAGE = [&](int buf, int kk) {
#pragma unroll
    for (int r = 0; r < 2; ++r) {
      int u = r * 256 + tid;
      int row = u >> 2, sl = u & 3;
      int c = sl ^ ((row >> 1) & 3);
      __builtin_amdgcn_global_load_lds(GAS(A + (size_t)(m0 + row) * K + kk + c * 8),
                                       LAS(&lA[buf][u * 8]), 16, 0, 0);
      __builtin_amdgcn_global_load_lds(GAS(BT + (size_t)(n0 + row) * K + kk + c * 8),
                                       LAS(&lB[buf][u * 8]), 16, 0, 0);
    }
  };

  const int nt = K >> 5;
  STAGE(0, 0);
  STAGE(1, 32);
  STAGE(2, 64);
  int buf = 0;
  for (int t = 0; t < nt; ++t) {
    if (t < nt - 2) WAITVM(8); else if (t == nt - 2) WAITVM(4); else WAITVM(0);
    __builtin_amdgcn_s_barrier();
    bx8 af[4], bq[4];
#pragma unroll
    for (int i = 0; i < 4; ++i) {
      int row = wr * 64 + i * 16 + lr;
      af[i] = *(const bx8*)&lA[buf][row * 32 + (g ^ ((row >> 1) & 3)) * 8];
      int col = wc * 64 + i * 16 + lr;
      bq[i] = *(const bx8*)&lB[buf][col * 32 + (g ^ ((col >> 1) & 3)) * 8];
    }
    WAITLG0();
    __builtin_amdgcn_s_barrier();
    if (t + 3 < nt) STAGE(buf, (t + 3) * 32);
#pragma unroll
    for (int i = 0; i < 4; ++i)
#pragma unroll
      for (int j = 0; j < 4; ++j)
        acc[i][j] = __builtin_amdgcn_mfma_f32_16x16x32_bf16(bq[j], af[i], acc[i][j], 0, 0, 0);
    buf = (buf == 2) ? 0 : buf + 1;
  }

#pragma unroll
  for (int i = 0; i < 4; ++i) {
    const int m = m0 + wr * 64 + i * 16 + lr;
#pragma unroll
    for (int j = 0; j < 4; ++j) {
      const int nc = n0 + wc * 64 + j * 16 + g * 4;
      const float4 bv = *(const float4*)(bvec + nc);
      float v0 = acc[i][j][0] + bv.x, v1 = acc[i][j][1] + bv.y;
      float v2 = acc[i][j][2] + bv.z, v3 = acc[i][j][3] + bv.w;
      if constexpr (EP == 1) {
        v0 = 0.5f * v0 * (1.0f + erff(v0 * 0.70710678118654752f));
        v1 = 0.5f * v1 * (1.0f + erff(v1 * 0.70710678118654752f));
        v2 = 0.5f * v2 * (1.0f + erff(v2 * 0.70710678118654752f));
        v3 = 0.5f * v3 * (1.0f + erff(v3 * 0.70710678118654752f));
      }
      if constexpr (EP == 1) {
        ushort4 st;
        st.x = f2bf(v0); st.y = f2bf(v1); st.z = f2bf(v2); st.w = f2bf(v3);
        *(ushort4*)(outb + (size_t)m * N + nc) = st;
      } else {  // EP 4
        const int s = m & 255, b = m >> 8;
        if (nc < 512) {
          ushort4 st;
          st.x = f2bf(v0); st.y = f2bf(v1); st.z = f2bf(v2); st.w = f2bf(v3);
          const int region = nc >> 8;        // 0 = q, 1 = k
          const int h = (nc >> 5) & 7, d0 = nc & 31;
          *(ushort4*)(outb + (size_t)region * QKV_REGION +
                      (size_t)(b * 8 + h) * 8192 + s * 32 + d0) = st;
        } else {
          unsigned short* vTp = (unsigned short*)resid;
          const int hv = nc - 512;
          const int h = hv >> 5, d0 = hv & 31;
          const int jj = (s & 3) + 4 * ((s >> 4) & 1);
          const int ub = (s >> 5) * 128 + ((s >> 2) & 3) * 32 + d0;
          unsigned short* base = vTp + (size_t)(b * 8 + h) * 8192;
          const float vv[4] = {v0, v1, v2, v3};
#pragma unroll
          for (int r = 0; r < 4; ++r) {
            int u = ub + r;
            int up = (u & ~7) | ((u & 7) ^ ((u >> 3) & 7));
            base[up * 8 + jj] = f2bf(vv[r]);
          }
        }
      }
    }
  }
}

// ---------- GEMM 32x256 + residual + FUSED LN (2-buffer, 4 blocks/CU) ----------
// EP 2: v = acc + bvec + col_bias[m&255][nc] + x_res   (proj path)
// EP 3: v = acc + bvec + x_res                          (W3 path)
// LNM 0: hn = (v-mean)*rs*lnw+lnb; LNM 1: stats[m]=(mean,rs).
template <int EP, int LNM>
__global__ __launch_bounds__(256) void gemm_ln_kernel(const unsigned short* __restrict__ A,
                                                      const unsigned short* __restrict__ BT,
                                                      const float* __restrict__ bvec,
                                                      const float* __restrict__ cbias,
                                                      float* __restrict__ resid,
                                                      const float* __restrict__ lnw,
                                                      const float* __restrict__ lnb,
                                                      unsigned short* __restrict__ hn,
                                                      float2* __restrict__ stats,
                                                      int K) {
  __shared__ unsigned short lA[2][32 * 32];
  __shared__ unsigned short lB[2][256 * 32];
  __shared__ float2 red[4][32];
  const int tid = threadIdx.x;
  const int lane = tid & 63, w = tid >> 6;
  const int g = lane >> 4, lr = lane & 15;
  const int m0 = blockIdx.x * 32;
  fx4 acc[2][4] = {};

  auto STAGE = [&](int buf, int kk) {
    {
      int u = tid & 127;  // duplicated across thread halves (identical data)
      int row = u >> 2, sl = u & 3;
      int c = sl ^ ((row >> 1) & 3);
      __builtin_amdgcn_global_load_lds(GAS(A + (size_t)(m0 + row) * K + kk + c * 8),
                                       LAS(&lA[buf][u * 8]), 16, 0, 0);
    }
#pragma unroll
    for (int r = 0; r < 4; ++r) {
      int u = r * 256 + tid;
      int row = u >> 2, sl = u & 3;
      int c = sl ^ ((row >> 1) & 3);
      __builtin_amdgcn_global_load_lds(GAS(BT + (size_t)row * K + kk + c * 8),
                                       LAS(&lB[buf][u * 8]), 16, 0, 0);
    }
  };

  const int nt = K >> 5;
  STAGE(0, 0);
  STAGE(1, 32);
  for (int t = 0; t < nt; ++t) {
    if (t == nt - 1) WAITVM(0); else WAITVM(5);
    __builtin_amdgcn_s_barrier();
    const int buf = t & 1;
    bx8 af[2], bq[4];
#pragma unroll
    for (int i = 0; i < 2; ++i) {
      int row = i * 16 + lr;
      af[i] = *(const bx8*)&lA[buf][row * 32 + (g ^ ((row >> 1) & 3)) * 8];
    }
#pragma unroll
    for (int j = 0; j < 4; ++j) {
      int col = w * 64 + j * 16 + lr;
      bq[j] = *(const bx8*)&lB[buf][col * 32 + (g ^ ((col >> 1) & 3)) * 8];
    }
    WAITLG0();
    __builtin_amdgcn_s_barrier();
    if (t + 2 < nt) STAGE(buf, (t + 2) * 32);
#pragma unroll
    for (int i = 0; i < 2; ++i)
#pragma unroll
      for (int j = 0; j < 4; ++j)
        acc[i][j] = __builtin_amdgcn_mfma_f32_16x16x32_bf16(bq[j], af[i], acc[i][j], 0, 0, 0);
  }

  float s[2] = {0.f, 0.f}, q[2] = {0.f, 0.f};
#pragma unroll
  for (int i = 0; i < 2; ++i) {
    const int m = m0 + i * 16 + lr;
#pragma unroll
    for (int j = 0; j < 4; ++j) {
      const int nc = w * 64 + j * 16 + g * 4;
      const float4 bv = *(const float4*)(bvec + nc);
      float v0 = acc[i][j][0] + bv.x, v1 = acc[i][j][1] + bv.y;
      float v2 = acc[i][j][2] + bv.z, v3 = acc[i][j][3] + bv.w;
      if constexpr (EP == 2) {
        const float4 cb = *(const float4*)(cbias + (size_t)(m & 255) * 256 + nc);
        v0 += cb.x; v1 += cb.y; v2 += cb.z; v3 += cb.w;
      }
      float4* rp = (float4*)(resid + (size_t)m * 256 + nc);
      float4 old = *rp;
      v0 += old.x; v1 += old.y; v2 += old.z; v3 += old.w;
      *rp = make_float4(v0, v1, v2, v3);
      acc[i][j][0] = v0; acc[i][j][1] = v1; acc[i][j][2] = v2; acc[i][j][3] = v3;
      s[i] += v0 + v1 + v2 + v3;
      q[i] += v0 * v0 + v1 * v1 + v2 * v2 + v3 * v3;
    }
  }
#pragma unroll
  for (int i = 0; i < 2; ++i) {
    s[i] += __shfl_xor(s[i], 16); s[i] += __shfl_xor(s[i], 32);
    q[i] += __shfl_xor(q[i], 16); q[i] += __shfl_xor(q[i], 32);
  }
  if (lane < 16) {
#pragma unroll
    for (int i = 0; i < 2; ++i) red[w][i * 16 + lr] = make_float2(s[i], q[i]);
  }
  __syncthreads();
  float mean[2], rs[2];
#pragma unroll
  for (int i = 0; i < 2; ++i) {
    float2 r0 = red[0][i * 16 + lr], r1 = red[1][i * 16 + lr];
    float2 r2 = red[2][i * 16 + lr], r3 = red[3][i * 16 + lr];
    float S = r0.x + r1.x + r2.x + r3.x;
    float Q = r0.y + r1.y + r2.y + r3.y;
    mean[i] = S * (1.0f / 256.0f);
    rs[i] = rsqrtf(Q * (1.0f / 256.0f) - mean[i] * mean[i] + 1e-5f);
  }
  if constexpr (LNM == 1) {
    if (w == 0 && g == 0) {
#pragma unroll
      for (int i = 0; i < 2; ++i) stats[m0 + i * 16 + lr] = make_float2(mean[i], rs[i]);
    }
  } else {
#pragma unroll
    for (int i = 0; i < 2; ++i) {
      const int m = m0 + i * 16 + lr;
#pragma unroll
      for (int j = 0; j < 4; ++j) {
        const int nc = w * 64 + j * 16 + g * 4;
        const float4 gv = *(const float4*)(lnw + nc);
        const float4 bv2 = *(const float4*)(lnb + nc);
        ushort4 st;
        st.x = f2bf((acc[i][j][0] - mean[i]) * rs[i] * gv.x + bv2.x);
        st.y = f2bf((acc[i][j][1] - mean[i]) * rs[i] * gv.y + bv2.y);
        st.z = f2bf((acc[i][j][2] - mean[i]) * rs[i] * gv.z + bv2.z);
        st.w = f2bf((acc[i][j][3] - mean[i]) * rs[i] * gv.w + bv2.w);
        *(ushort4*)(hn + (size_t)m * 256 + nc) = st;
      }
    }
  }
}

// ---------- fused W2+swiglu, 8-WAVE (512 threads): BM=64/BN=128, 3-ring depth-2 ----------
// w2f was L2-latency-bound at 8 waves/CU (19% occ, L2 at 29% of peak). 512-thread
// blocks double resident waves (16/CU at same 60KB LDS, 2 blocks/CU). Per wave:
// one 16-col strip of a AND gate (aA[4]+aG[4], 32 VGPR). Staging wave-uniform at
// 3 loads/thread (A unit duplicated across thread halves, gemm_ln-proven trick).
// Wait ladder: steady vmcnt(6) = 2 stages x 3 loads, drain 3 -> 0.
__global__ __launch_bounds__(512) void gemm_w2f512_kernel(const unsigned short* __restrict__ A,
                                                          const unsigned short* __restrict__ BT,
                                                          const float* __restrict__ b2,
                                                          unsigned short* __restrict__ gout) {
  __shared__ unsigned short lA[3][64 * 32];
  __shared__ unsigned short lBa[3][128 * 32];
  __shared__ unsigned short lBg[3][128 * 32];
  const int tid = threadIdx.x;
  const int lane = tid & 63, w = tid >> 6;   // w in [0,8)
  const int g = lane >> 4, lr = lane & 15;
  const int m0 = blockIdx.y * 64, n0 = blockIdx.x * 128;
  fx4 aA[4] = {}, aG[4] = {};

  auto STAGE = [&](int buf, int kk) {
    {
      int u = tid & 255;  // A: 256 units, duplicated across thread halves
      int row = u >> 2, sl = u & 3;
      int c = sl ^ ((row >> 1) & 3);
      __builtin_amdgcn_global_load_lds(GAS(A + (size_t)(m0 + row) * 1024 + kk + c * 8),
                                       LAS(&lA[buf][u * 8]), 16, 0, 0);
    }
    {
      int u = tid;        // Ba: 512 units (rows 0..127)
      int row = u >> 2, sl = u & 3;
      int c = sl ^ ((row >> 1) & 3);
      __builtin_amdgcn_global_load_lds(GAS(BT + (size_t)(n0 + row) * 1024 + kk + c * 8),
                                       LAS(&lBa[buf][u * 8]), 16, 0, 0);
      __builtin_amdgcn_global_load_lds(GAS(BT + (size_t)(256 + n0 + row) * 1024 + kk + c * 8),
                                       LAS(&lBg[buf][u * 8]), 16, 0, 0);
    }
  };

  STAGE(0, 0);
  STAGE(1, 32);
  STAGE(2, 64);
  int buf = 0;
  for (int t = 0; t < 32; ++t) {
    if (t < 30) WAITVM(6); else if (t == 30) WAITVM(3); else WAITVM(0);
    __builtin_amdgcn_s_barrier();
    bx8 af[4], ba, bg;
#pragma unroll
    for (int i = 0; i < 4; ++i) {
      int row = i * 16 + lr;
      af[i] = *(const bx8*)&lA[buf][row * 32 + (g ^ ((row >> 1) & 3)) * 8];
    }
    {
      int col = w * 16 + lr;
      int sw = (g ^ ((col >> 1) & 3)) * 8;
      ba = *(const bx8*)&lBa[buf][col * 32 + sw];
      bg = *(const bx8*)&lBg[buf][col * 32 + sw];
    }
    WAITLG0();
    __builtin_amdgcn_s_barrier();
    if (t + 3 < 32) STAGE(buf, (t + 3) * 32);  // reuse just-consumed buffer
#pragma unroll
    for (int i = 0; i < 4; ++i) {
      aA[i] = __builtin_amdgcn_mfma_f32_16x16x32_bf16(ba, af[i], aA[i], 0, 0, 0);
      aG[i] = __builtin_amdgcn_mfma_f32_16x16x32_bf16(bg, af[i], aG[i], 0, 0, 0);
    }
    buf = (buf == 2) ? 0 : buf + 1;
  }

  const int nc = n0 + w * 16 + g * 4;
  const float4 bva = *(const float4*)(b2 + nc);
  const float4 bvg = *(const float4*)(b2 + 256 + nc);
#pragma unroll
  for (int i = 0; i < 4; ++i) {
    const int m = m0 + i * 16 + lr;
    float a0 = aA[i][0] + bva.x, a1 = aA[i][1] + bva.y;
    float a2 = aA[i][2] + bva.z, a3 = aA[i][3] + bva.w;
    float g0 = aG[i][0] + bvg.x, g1 = aG[i][1] + bvg.y;
    float g2 = aG[i][2] + bvg.z, g3 = aG[i][3] + bvg.w;
    ushort4 st;
    st.x = f2bf(a0 / (1.0f + __expf(-g0)));
    st.y = f2bf(a1 / (1.0f + __expf(-g1)));
    st.z = f2bf(a2 / (1.0f + __expf(-g2)));
    st.w = f2bf(a3 / (1.0f + __expf(-g3)));
    *(ushort4*)(gout + (size_t)m * 256 + nc) = st;
  }
}

// ---------- fused attention v5: coalesced per-head Q/K/V (qT/kT/vT) + setprio ----------
__global__ __launch_bounds__(256) void attn_kernel(const unsigned short* __restrict__ qT,
                                                   const unsigned short* __restrict__ vT,
                                                   const float* __restrict__ cbias,
                                                   unsigned short* __restrict__ attnb) {
  __shared__ unsigned short Kl[256 * 32];
  __shared__ unsigned short Vl[1024 * 8];
  const int bh = blockIdx.x, b = bh >> 3, h = bh & 7;
  const int tid = threadIdx.x, lane = tid & 63, w = tid >> 6;
  const int g = lane >> 4, lr = lane & 15;
  const unsigned short* qTb = qT + (size_t)bh * 8192;
  const unsigned short* kTb = qT + QKV_REGION + (size_t)bh * 8192;
  const unsigned short* vTb = vT + (size_t)bh * 8192;
#pragma unroll
  for (int r = 0; r < 4; ++r) {
    int u = r * 256 + tid;
    int s = u >> 2, sl = u & 3;
    int c = sl ^ ((s >> 1) & 3);
    __builtin_amdgcn_global_load_lds(GAS(kTb + s * 32 + c * 8), LAS(&Kl[u * 8]), 16, 0, 0);
    __builtin_amdgcn_global_load_lds(GAS(vTb + u * 8), LAS(&Vl[u * 8]), 16, 0, 0);
  }
  asm volatile("s_waitcnt vmcnt(0)" ::: "memory");
  __syncthreads();
  const float scale = 0.17677669529663689f;
  const fx4 zero = {0.f, 0.f, 0.f, 0.f};
#pragma unroll 1
  for (int it = 0; it < 4; ++it) {
    const int t = it * 64 + w * 16 + lr;
    bx8 qf = *(const bx8*)(qTb + t * 32 + g * 8);
    float p[16][4];
    float mx = -1e30f;
    __builtin_amdgcn_s_setprio(1);
#pragma unroll
    for (int n = 0; n < 16; ++n) {
      int sr = n * 16 + lr;
      bx8 kf = *(const bx8*)&Kl[sr * 32 + (g ^ ((sr >> 1) & 3)) * 8];
      fx4 sc = __builtin_amdgcn_mfma_f32_16x16x32_bf16(kf, qf, zero, 0, 0, 0);
      const float4 cb = *(const float4*)(cbias + (size_t)t * 256 + n * 16 + g * 4);
      p[n][0] = sc[0] * scale + cb.x;
      p[n][1] = sc[1] * scale + cb.y;
      p[n][2] = sc[2] * scale + cb.z;
      p[n][3] = sc[3] * scale + cb.w;
      mx = fmaxf(mx, fmaxf(fmaxf(p[n][0], p[n][1]), fmaxf(p[n][2], p[n][3])));
    }
    __builtin_amdgcn_s_setprio(0);
    mx = fmaxf(mx, __shfl_xor(mx, 16));
    mx = fmaxf(mx, __shfl_xor(mx, 32));
    float sum = 0.f;
    bx8 bq[8];
#pragma unroll
    for (int c = 0; c < 8; ++c) {
      union { bx8 v; unsigned short u[8]; } pk;
#pragma unroll
      for (int jj = 0; jj < 8; ++jj) {
        float e = __expf(p[2 * c + (jj >> 2)][jj & 3] - mx);
        sum += e;
        pk.u[jj] = f2bf(e);
      }
      bq[c] = pk.v;
    }
    sum += __shfl_xor(sum, 16);
    sum += __shfl_xor(sum, 32);
    const float inv = 1.0f / sum;
    fx4 oa0 = zero, oa1 = zero;
    __builtin_amdgcn_s_setprio(1);
#pragma unroll
    for (int c = 0; c < 8; ++c) {
      int u0 = c * 128 + g * 32 + lr;
      int u0p = (u0 & ~7) | ((u0 & 7) ^ ((u0 >> 3) & 7));
      bx8 vf0 = *(const bx8*)&Vl[u0p * 8];
      oa0 = __builtin_amdgcn_mfma_f32_16x16x32_bf16(vf0, bq[c], oa0, 0, 0, 0);
      int u1 = u0 + 16;
      int u1p = (u1 & ~7) | ((u1 & 7) ^ ((u1 >> 3) & 7));
      bx8 vf1 = *(const bx8*)&Vl[u1p * 8];
      oa1 = __builtin_amdgcn_mfma_f32_16x16x32_bf16(vf1, bq[c], oa1, 0, 0, 0);
    }
    __builtin_amdgcn_s_setprio(0);
    ushort4 o0, o1;
    o0.x = f2bf(oa0[0] * inv); o0.y = f2bf(oa0[1] * inv);
    o0.z = f2bf(oa0[2] * inv); o0.w = f2bf(oa0[3] * inv);
    o1.x = f2bf(oa1[0] * inv); o1.y = f2bf(oa1[1] * inv);
    o1.z = f2bf(oa1[2] * inv); o1.w = f2bf(oa1[3] * inv);
    unsigned short* orow = attnb + (size_t)(b * 256 + t) * 256 + h * 32;
    *(ushort4*)(orow + 4 * g) = o0;
    *(ushort4*)(orow + 16 + 4 * g) = o1;
  }
}

// ---------- orchestration ----------
extern "C" void kernel_launch(void* const* d_in, const int* in_sizes, int n_in,
                              void* d_out, int out_size, void* d_ws, size_t ws_size,
                              hipStream_t stream) {
  (void)in_sizes; (void)n_in; (void)out_size; (void)ws_size;
  const float* x     = (const float*)d_in[0];
  const float* cemb  = (const float*)d_in[1];
  const float* pemb  = (const float*)d_in[2];
  const float* cbias = (const float*)d_in[3];
  const float* ln1g  = (const float*)d_in[4];
  const float* ln1b  = (const float*)d_in[5];
  const float* qkvw  = (const float*)d_in[6];
  const float* qkvb  = (const float*)d_in[7];
  const float* outw  = (const float*)d_in[8];
  const float* outbv = (const float*)d_in[9];
  const float* ln2g  = (const float*)d_in[10];
  const float* ln2b  = (const float*)d_in[11];
  const float* w1    = (const float*)d_in[12];
  const float* b1    = (const float*)d_in[13];
  const float* w2    = (const float*)d_in[14];
  const float* b2    = (const float*)d_in[15];
  const float* w3    = (const float*)d_in[16];
  const float* b3    = (const float*)d_in[17];
  const float* fing  = (const float*)d_in[18];
  const float* finb  = (const float*)d_in[19];

  char* ws = (char*)d_ws;
  float* x_res = (float*)(ws);
  unsigned short* hn   = (unsigned short*)(ws + 33554432);
  unsigned short* big  = (unsigned short*)(ws + 50331648);   // qT base / u base
  unsigned short* vT   = (unsigned short*)(ws + 83886080);   // qT + 2*QKV_REGION shorts
  unsigned short* wT   = (unsigned short*)(ws + 117440512);
  float2* stats = (float2*)(ws + 130809856);
  float* part  = (float*)big;  // mean partials: big dead by then

  unsigned short* qkvwT = wT;                 // 6*768*256
  unsigned short* outwT = wT + 1179648;       // 6*256*256
  unsigned short* w1T   = wT + 1572864;       // 6*1024*256
  unsigned short* w2T   = wT + 3145728;       // 6*512*1024
  unsigned short* w3T   = wT + 6291456;       // 6*256*256

  wtrans_kernel<<<dim3(12, 4, 6), 256, 0, stream>>>(qkvw, qkvwT, 256, 768);
  wtrans_kernel<<<dim3(4, 4, 6), 256, 0, stream>>>(outw, outwT, 256, 256);
  wtrans_kernel<<<dim3(16, 4, 6), 256, 0, stream>>>(w1, w1T, 256, 1024);
  wtrans_kernel<<<dim3(8, 16, 6), 256, 0, stream>>>(w2, w2T, 1024, 512);
  wtrans_kernel<<<dim3(4, 4, 6), 256, 0, stream>>>(w3, w3T, 256, 256);
  embed_ln_kernel<<<8192, 256, 0, stream>>>((const float4*)x, (const float4*)cemb,
                                            (const float4*)pemb, ln1g, ln1b,
                                            (float4*)x_res, hn);
  for (int l = 0; l < 6; ++l) {
    gemm_kernel<4><<<dim3(6, 256), 256, 0, stream>>>(hn, qkvwT + (size_t)l * 196608,
                                                     qkvb + l * 768, (float*)vT, big,
                                                     768, 256);
    attn_kernel<<<1024, 256, 0, stream>>>(big, vT, cbias, hn);
    gemm_ln_kernel<2, 0><<<1024, 256, 0, stream>>>(hn, outwT + (size_t)l * 65536,
                                                   outbv + l * 256, cbias, x_res,
                                                   ln2g + l * 256, ln2b + l * 256, hn,
                                                   nullptr, 256);
    gemm_kernel<1><<<dim3(8, 256), 256, 0, stream>>>(hn, w1T + (size_t)l * 262144,
                                                     b1 + l * 1024, nullptr, big,
                                                     1024, 256);
    gemm_w2f512_kernel<<<dim3(2, 512), 512, 0, stream>>>(big, w2T + (size_t)l * 524288,
                                                         b2 + l * 512, hn);
    if (l < 5) {
      gemm_ln_kernel<3, 0><<<1024, 256, 0, stream>>>(hn, w3T + (size_t)l * 65536,
                                                     b3 + l * 256, nullptr, x_res,
                                                     ln1g + (l + 1) * 256,
                                                     ln1b + (l + 1) * 256, hn,
                                                     nullptr, 256);
    } else {
      gemm_ln_kernel<3, 1><<<1024, 256, 0, stream>>>(hn, w3T + (size_t)l * 65536,
                                                     b3 + l * 256, nullptr, x_res,
                                                     nullptr, nullptr, nullptr,
                                                     stats, 256);
    }
  }
  mean_part_kernel<<<dim3(128, 2), 256, 0, stream>>>(x_res, stats, part);
  mean_fin_kernel<<<128, 256, 0, stream>>>(part, fing, finb, (float*)d_out);
}